// Round 2
// baseline (2237.667 us; speedup 1.0000x reference)
//
#include <hip/hip_runtime.h>
#include <hip/hip_bf16.h>
#include <cstdint>

#define NEG_SLOPE 0.2f

// ---------- bf16 helpers ----------
__device__ __forceinline__ float us2f(unsigned short u) {
    union { unsigned int i; float f; } c; c.i = ((unsigned int)u) << 16; return c.f;
}
__device__ __forceinline__ unsigned short f2us(float f) {
    union { float f; unsigned int i; } c; c.f = f;
    unsigned int x = c.i;
    unsigned int r = (x + 0x7fffu + ((x >> 16) & 1u)) >> 16;   // RNE
    return (unsigned short)r;
}
// load element i of a possibly-bf16 (bf=1) or f32 (bf=0) tensor
__device__ __forceinline__ float ldx(const void* p, int i, int bf) {
    return bf ? us2f(((const unsigned short*)p)[i]) : ((const float*)p)[i];
}

// ---------- runtime dtype probes ----------
// flags[0] = 1 if float tensors are bf16, 0 if f32
// flags[1] = 1 if edge_index is int64, 0 if int32
__global__ void k_detect(const unsigned short* __restrict__ x16,
                         const unsigned int* __restrict__ ei,
                         int* __restrict__ flags) {
    if (threadIdx.x == 0 && blockIdx.x == 0) {
        int cnt = 0;
        for (int i = 0; i < 1024; ++i) {
            const unsigned short u = x16[2 * i];     // low half of f32 OR a bf16 value
            const int e = (u >> 7) & 0xFF;           // exponent field if bf16
            if (e < 100 || e > 160) ++cnt;           // ~76% for uniform bits, ~0% for bf16 N(0,1)
        }
        flags[0] = (cnt < 256) ? 1 : 0;
        int is64 = 1;
        for (int i = 0; i < 64; ++i)
            if (ei[2 * i + 1] != 0u) { is64 = 0; break; }
        flags[1] = is64;
    }
}

__device__ __forceinline__ int edge_at(const void* ei, int f64, long long idx) {
    if (f64) return (int)((const long long*)ei)[idx];
    return ((const int*)ei)[idx];
}

// ---------- CSR build ----------
__global__ void k_hist(const void* __restrict__ ei, const int* __restrict__ flags,
                       int* __restrict__ deg, int E, int N) {
    const int f64 = flags[1];
    const int EP = E + N;
    for (int e = blockIdx.x * blockDim.x + threadIdx.x; e < EP; e += gridDim.x * blockDim.x) {
        int dst = (e < E) ? edge_at(ei, f64, (long long)E + e) : (e - E);
        atomicAdd(&deg[dst], 1);
    }
}

__global__ __launch_bounds__(1024) void k_scan(const int* __restrict__ deg,
                                               int* __restrict__ off, int N) {
    __shared__ int tmp[1024];
    __shared__ int carry_s;
    const int t = threadIdx.x;
    if (t == 0) carry_s = 0;
    __syncthreads();
    for (int base = 0; base < N; base += 1024) {
        const int idx = base + t;
        const int v = (idx < N) ? deg[idx] : 0;
        tmp[t] = v;
        __syncthreads();
        for (int s = 1; s < 1024; s <<= 1) {
            int add = (t >= s) ? tmp[t - s] : 0;
            __syncthreads();
            tmp[t] += add;
            __syncthreads();
        }
        const int carry = carry_s;
        if (idx < N) off[idx] = carry + tmp[t] - v;   // exclusive
        __syncthreads();
        if (t == 1023) carry_s = carry + tmp[1023];
        __syncthreads();
    }
    if (t == 0) off[N] = carry_s;
}

__global__ void k_scatter(const void* __restrict__ ei, const int* __restrict__ flags,
                          const int* __restrict__ coff, int* __restrict__ cpos,
                          int* __restrict__ csrc, int E, int N) {
    const int f64 = flags[1];
    const int EP = E + N;
    for (int e = blockIdx.x * blockDim.x + threadIdx.x; e < EP; e += gridDim.x * blockDim.x) {
        int src, dst;
        if (e < E) { src = edge_at(ei, f64, e); dst = edge_at(ei, f64, (long long)E + e); }
        else       { src = dst = e - E; }
        const int p = atomicAdd(&cpos[dst], 1);
        csrc[coff[dst] + p] = src;
    }
}

// ---------- GEMM: Y[n, yc0..yc0+64) = X[n,0:128] @ W[0:128, wc0..wc0+64) ----------
// XRAW: X is a raw input tensor (dtype per flag); else X is f32 workspace.
// W is raw input (dtype per flag). Y f32.
template <bool XRAW>
__global__ __launch_bounds__(256) void k_gemm(const void* __restrict__ Xv,
                                              const void* __restrict__ Wv,
                                              float* __restrict__ Y,
                                              const int* __restrict__ flags,
                                              int N, int wstride, int wcolBase) {
    __shared__ float Xs[128][68];   // [k][row], padded
    __shared__ float Ws[128][64];   // [k][col]
    const int bf   = flags[0];
    const int t    = threadIdx.x;
    const int row0 = blockIdx.x * 64;
    const int wc0  = wcolBase + blockIdx.y * 64;
    const int yc0  = blockIdx.y * 64;

    for (int i = t; i < 8192; i += 256) {           // 64 rows x 128 k
        const int r = i >> 7, k = i & 127;
        const int gr = row0 + r;
        float v = 0.f;
        if (gr < N)
            v = XRAW ? ldx(Xv, gr * 128 + k, bf) : ((const float*)Xv)[gr * 128 + k];
        Xs[k][r] = v;
    }
    for (int i = t; i < 8192; i += 256) {           // 128 k x 64 cols
        const int k = i >> 6, c = i & 63;
        Ws[k][c] = ldx(Wv, k * wstride + wc0 + c, bf);
    }
    __syncthreads();

    const int tx = (t & 15) * 4;    // col within tile
    const int ty = (t >> 4) * 4;    // row within tile
    float acc[4][4] = {};
#pragma unroll 4
    for (int k = 0; k < 128; ++k) {
        const float4 xv = *(const float4*)(&Xs[k][ty]);
        const float4 wv = *(const float4*)(&Ws[k][tx]);
        const float xr[4] = { xv.x, xv.y, xv.z, xv.w };
        const float wr[4] = { wv.x, wv.y, wv.z, wv.w };
#pragma unroll
        for (int i = 0; i < 4; ++i)
#pragma unroll
            for (int j = 0; j < 4; ++j)
                acc[i][j] = fmaf(xr[i], wr[j], acc[i][j]);
    }
#pragma unroll
    for (int i = 0; i < 4; ++i) {
        const int gr = row0 + ty + i;
        if (gr < N) {
            float4 o = make_float4(acc[i][0], acc[i][1], acc[i][2], acc[i][3]);
            *(float4*)(&Y[gr * 128 + yc0 + tx]) = o;
        }
    }
}

// ---------- attention scores ----------
// C=32: 4 heads over 128 cols -> s arrays [N*4].  C=128: one head -> s arrays [N].
// a_src/a_dst raw inputs at element offset aoff.
template <int C>
__global__ __launch_bounds__(256) void k_scores(const float* __restrict__ H,
                                                const void* __restrict__ a_src,
                                                const void* __restrict__ a_dst,
                                                int aoff,
                                                const int* __restrict__ flags,
                                                float* __restrict__ ssrc, float* __restrict__ sdst,
                                                int N) {
    const int bf   = flags[0];
    const int wave = blockIdx.x * (blockDim.x >> 6) + (threadIdx.x >> 6);
    const int lane = threadIdx.x & 63;
    if (wave >= N) return;
    const float as0 = ldx(a_src, aoff + lane, bf);
    const float as1 = ldx(a_src, aoff + lane + 64, bf);
    const float ad0 = ldx(a_dst, aoff + lane, bf);
    const float ad1 = ldx(a_dst, aoff + lane + 64, bf);
    const float h0 = H[wave * 128 + lane];
    const float h1 = H[wave * 128 + lane + 64];
    float ps0 = h0 * as0, ps1 = h1 * as1;
    float pd0 = h0 * ad0, pd1 = h1 * ad1;
    if (C == 32) {
#pragma unroll
        for (int mk = 1; mk <= 16; mk <<= 1) {
            ps0 += __shfl_xor(ps0, mk); ps1 += __shfl_xor(ps1, mk);
            pd0 += __shfl_xor(pd0, mk); pd1 += __shfl_xor(pd1, mk);
        }
        if (lane == 0)  { ssrc[wave*4+0]=ps0; ssrc[wave*4+2]=ps1; sdst[wave*4+0]=pd0; sdst[wave*4+2]=pd1; }
        if (lane == 32) { ssrc[wave*4+1]=ps0; ssrc[wave*4+3]=ps1; sdst[wave*4+1]=pd0; sdst[wave*4+3]=pd1; }
    } else {
        float ps = ps0 + ps1, pd = pd0 + pd1;
#pragma unroll
        for (int mk = 1; mk <= 32; mk <<= 1) { ps += __shfl_xor(ps, mk); pd += __shfl_xor(pd, mk); }
        if (lane == 0) { ssrc[wave] = ps; sdst[wave] = pd; }
    }
}

// ---------- per-node softmax + aggregation; one wave per node ----------
// MODE 0: out = elu(acc + bias + resid)  with resid = raw input (dtype flag)
// MODE 1: out = elu(acc + bias + resid)  with resid = f32 workspace
// MODE 2: out += acc                     (layer 3, per head; no bias/resid)
template <int NUMS, int MODE>
__global__ __launch_bounds__(256) void k_agg(const int* __restrict__ coff,
                                             const int* __restrict__ csrc,
                                             const float* __restrict__ ssrc,
                                             const float* __restrict__ sdst,
                                             const float* __restrict__ H,
                                             const void* __restrict__ bias,
                                             const void* __restrict__ resid,
                                             const int* __restrict__ flags,
                                             float* __restrict__ out, int N) {
    const int bf   = flags[0];
    const int n    = blockIdx.x * (blockDim.x >> 6) + (threadIdx.x >> 6);
    const int lane = threadIdx.x & 63;
    if (n >= N) return;
    const int beg = coff[n], end = coff[n + 1];

    float sd[NUMS];
#pragma unroll
    for (int h = 0; h < NUMS; ++h) sd[h] = sdst[n * NUMS + h];

    float m[NUMS];
#pragma unroll
    for (int h = 0; h < NUMS; ++h) m[h] = -1e30f;
    for (int e = beg + lane; e < end; e += 64) {
        const int s = csrc[e];
#pragma unroll
        for (int h = 0; h < NUMS; ++h) {
            float v = ssrc[s * NUMS + h] + sd[h];
            v = v >= 0.f ? v : NEG_SLOPE * v;
            m[h] = fmaxf(m[h], v);
        }
    }
#pragma unroll
    for (int mk = 1; mk <= 32; mk <<= 1)
#pragma unroll
        for (int h = 0; h < NUMS; ++h) m[h] = fmaxf(m[h], __shfl_xor(m[h], mk));

    float z[NUMS] = {};
    for (int e = beg + lane; e < end; e += 64) {
        const int s = csrc[e];
#pragma unroll
        for (int h = 0; h < NUMS; ++h) {
            float v = ssrc[s * NUMS + h] + sd[h];
            v = v >= 0.f ? v : NEG_SLOPE * v;
            z[h] += expf(v - m[h]);
        }
    }
#pragma unroll
    for (int mk = 1; mk <= 32; mk <<= 1)
#pragma unroll
        for (int h = 0; h < NUMS; ++h) z[h] += __shfl_xor(z[h], mk);
    float inv[NUMS];
#pragma unroll
    for (int h = 0; h < NUMS; ++h) inv[h] = 1.f / (z[h] + 1e-16f);

    // phase 3: weighted gather; lane covers channels lane and lane+64
    float sdA, mA, ivA, sdB, mB, ivB;
    int hA, hB;
    if (NUMS == 4) {
        const bool hi = (lane >= 32);
        sdA = hi ? sd[1] : sd[0]; mA = hi ? m[1] : m[0]; ivA = hi ? inv[1] : inv[0];
        sdB = hi ? sd[3] : sd[2]; mB = hi ? m[3] : m[2]; ivB = hi ? inv[3] : inv[2];
        hA = hi ? 1 : 0; hB = hA + 2;
    } else {
        sdA = sdB = sd[0]; mA = mB = m[0]; ivA = ivB = inv[0]; hA = hB = 0;
    }
    float acc0 = 0.f, acc1 = 0.f;
    for (int e = beg; e < end; ++e) {
        const int s = csrc[e];
        const float* sp = &ssrc[s * NUMS];
        float v1 = sp[hA] + sdA; v1 = v1 >= 0.f ? v1 : NEG_SLOPE * v1;
        const float w1 = expf(v1 - mA) * ivA;
        float w2;
        if (NUMS == 4) {
            float v2 = sp[hB] + sdB; v2 = v2 >= 0.f ? v2 : NEG_SLOPE * v2;
            w2 = expf(v2 - mB) * ivB;
        } else w2 = w1;
        acc0 = fmaf(w1, H[s * 128 + lane], acc0);
        acc1 = fmaf(w2, H[s * 128 + lane + 64], acc1);
    }

    const int o = n * 128 + lane;
    if (MODE == 2) {
        out[o]      += acc0;
        out[o + 64] += acc1;
    } else {
        const float b0 = ldx(bias, lane, bf), b1 = ldx(bias, lane + 64, bf);
        float r0, r1;
        if (MODE == 0) { r0 = ldx(resid, o, bf); r1 = ldx(resid, o + 64, bf); }
        else           { r0 = ((const float*)resid)[o]; r1 = ((const float*)resid)[o + 64]; }
        const float v0 = acc0 + b0 + r0;
        const float v1 = acc1 + b1 + r1;
        out[o]      = v0 > 0.f ? v0 : expm1f(v0);
        out[o + 64] = v1 > 0.f ? v1 : expm1f(v1);
    }
}

// ---------- final: out = cast(acc/4 + b3 + x2) ----------
__global__ void k_final(const float* __restrict__ acc, const void* __restrict__ b3,
                        const float* __restrict__ x2, void* __restrict__ out,
                        const int* __restrict__ flags, int total) {
    const int bf = flags[0];
    for (int i = blockIdx.x * blockDim.x + threadIdx.x; i < total; i += gridDim.x * blockDim.x) {
        const int c = i & 127;
        const float v = acc[i] * 0.25f + ldx(b3, c, bf) + x2[i];
        if (bf) ((unsigned short*)out)[i] = f2us(v);
        else    ((float*)out)[i] = v;
    }
}

extern "C" void kernel_launch(void* const* d_in, const int* in_sizes, int n_in,
                              void* d_out, int out_size, void* d_ws, size_t ws_size,
                              hipStream_t stream) {
    const int N  = in_sizes[0] / 128;     // 100000
    const int E  = in_sizes[1] / 2;       // 800000
    const int EP = E + N;

    const void* x   = d_in[0];
    const void* ei  = d_in[1];
    const void* W1  = d_in[2];
    const void* as1 = d_in[3];
    const void* ad1 = d_in[4];
    const void* b1  = d_in[5];
    const void* W2  = d_in[6];
    const void* as2 = d_in[7];
    const void* ad2 = d_in[8];
    const void* b2  = d_in[9];
    const void* W3  = d_in[10];
    const void* as3 = d_in[11];
    const void* ad3 = d_in[12];
    const void* b3  = d_in[13];

    // workspace carve-up (~213 MB)
    char* p = (char*)d_ws;
    auto alloc = [&](size_t bytes) { char* r = p; p += (bytes + 255) & ~(size_t)255; return r; };
    int*   flags = (int*)alloc(8);
    int*   deg   = (int*)alloc((size_t)(N + 1) * 4);
    int*   coff  = (int*)alloc((size_t)(N + 1) * 4);
    int*   cpos  = (int*)alloc((size_t)N * 4);
    int*   csrc  = (int*)alloc((size_t)EP * 4);
    float* hbuf  = (float*)alloc((size_t)N * 128 * 4);
    float* x1b   = (float*)alloc((size_t)N * 128 * 4);
    float* x2b   = (float*)alloc((size_t)N * 128 * 4);
    float* accb  = (float*)alloc((size_t)N * 128 * 4);
    float* ssrc  = (float*)alloc((size_t)N * 4 * 4);
    float* sdst  = (float*)alloc((size_t)N * 4 * 4);

    hipMemsetAsync(deg,  0, (size_t)(N + 1) * 4, stream);
    hipMemsetAsync(cpos, 0, (size_t)N * 4, stream);
    hipMemsetAsync(accb, 0, (size_t)N * 128 * 4, stream);

    k_detect<<<1, 64, 0, stream>>>((const unsigned short*)x, (const unsigned int*)ei, flags);

    // CSR build (dst-sorted), reused by all 3 layers
    const int egrid = (EP + 255) / 256;
    k_hist<<<egrid, 256, 0, stream>>>(ei, flags, deg, E, N);
    k_scan<<<1, 1024, 0, stream>>>(deg, coff, N);
    k_scatter<<<egrid, 256, 0, stream>>>(ei, flags, coff, cpos, csrc, E, N);

    const dim3 ggrid((N + 63) / 64, 2);
    const int  ngrid = (N + 3) / 4;   // 4 waves (nodes) per 256-thr block

    // ---- layer 1: x1 = elu(gat1(x) + x)
    k_gemm<true ><<<ggrid, 256, 0, stream>>>(x,   W1, hbuf, flags, N, 128, 0);
    k_scores<32><<<ngrid, 256, 0, stream>>>(hbuf, as1, ad1, 0, flags, ssrc, sdst, N);
    k_agg<4, 0><<<ngrid, 256, 0, stream>>>(coff, csrc, ssrc, sdst, hbuf, b1, x,   flags, x1b, N);

    // ---- layer 2: x2 = elu(gat2(x1) + x1)
    k_gemm<false><<<ggrid, 256, 0, stream>>>(x1b, W2, hbuf, flags, N, 128, 0);
    k_scores<32><<<ngrid, 256, 0, stream>>>(hbuf, as2, ad2, 0, flags, ssrc, sdst, N);
    k_agg<4, 1><<<ngrid, 256, 0, stream>>>(coff, csrc, ssrc, sdst, hbuf, b2, x1b, flags, x2b, N);

    // ---- layer 3: mean over 4 heads, processed head-by-head
    for (int h = 0; h < 4; ++h) {
        k_gemm<false><<<ggrid, 256, 0, stream>>>(x2b, W3, hbuf, flags, N, 512, h * 128);
        k_scores<128><<<ngrid, 256, 0, stream>>>(hbuf, as3, ad3, h * 128, flags, ssrc, sdst, N);
        k_agg<1, 2><<<ngrid, 256, 0, stream>>>(coff, csrc, ssrc, sdst, hbuf,
                                               nullptr, nullptr, flags, accb, N);
    }

    k_final<<<2048, 256, 0, stream>>>(accb, b3, x2b, d_out, flags, N * 128);
}

// Round 4
// 1391.860 us; speedup vs baseline: 1.6077x; 1.6077x over previous
//
#include <hip/hip_runtime.h>
#include <hip/hip_bf16.h>
#include <cstdint>

#define NEG_SLOPE 0.2f

typedef __bf16 bf16x8 __attribute__((ext_vector_type(8)));
typedef float  floatx4 __attribute__((ext_vector_type(4)));

// ---------- bf16 helpers ----------
__device__ __forceinline__ float us2f(unsigned short u) {
    union { unsigned int i; float f; } c; c.i = ((unsigned int)u) << 16; return c.f;
}
__device__ __forceinline__ unsigned short f2us(float f) {
    union { float f; unsigned int i; } c; c.f = f;
    unsigned int x = c.i;
    unsigned int r = (x + 0x7fffu + ((x >> 16) & 1u)) >> 16;   // RNE
    return (unsigned short)r;
}
__device__ __forceinline__ float ldx(const void* p, int i, int bf) {
    return bf ? us2f(((const unsigned short*)p)[i]) : ((const float*)p)[i];
}
// split f32 into hi/lo bf16 planes
__device__ __forceinline__ void split2(float f, unsigned short& h, unsigned short& l) {
    h = f2us(f);
    l = f2us(f - us2f(h));
}

// ---------- runtime dtype probes ----------
__global__ void k_detect(const unsigned short* __restrict__ x16,
                         const unsigned int* __restrict__ ei,
                         int* __restrict__ flags) {
    if (threadIdx.x == 0 && blockIdx.x == 0) {
        int cnt = 0;
        for (int i = 0; i < 1024; ++i) {
            const unsigned short u = x16[2 * i];
            const int e = (u >> 7) & 0xFF;
            if (e < 100 || e > 160) ++cnt;
        }
        flags[0] = (cnt < 256) ? 1 : 0;      // bf16?
        int is64 = 1;
        for (int i = 0; i < 64; ++i)
            if (ei[2 * i + 1] != 0u) { is64 = 0; break; }
        flags[1] = is64;                      // int64?
    }
}

__device__ __forceinline__ int edge_at(const void* ei, int f64, long long idx) {
    if (f64) return (int)((const long long*)ei)[idx];
    return ((const int*)ei)[idx];
}

// ---------- CSR build ----------
__global__ void k_hist(const void* __restrict__ ei, const int* __restrict__ flags,
                       int* __restrict__ deg, int E, int N) {
    const int f64 = flags[1];
    const int EP = E + N;
    for (int e = blockIdx.x * blockDim.x + threadIdx.x; e < EP; e += gridDim.x * blockDim.x) {
        int dst = (e < E) ? edge_at(ei, f64, (long long)E + e) : (e - E);
        atomicAdd(&deg[dst], 1);
    }
}

__global__ __launch_bounds__(1024) void k_scan_a(const int* __restrict__ deg,
                                                 int* __restrict__ coff,
                                                 int* __restrict__ part, int N) {
    __shared__ int tmp[1024];
    const int t = threadIdx.x, idx = blockIdx.x * 1024 + t;
    const int v = (idx < N) ? deg[idx] : 0;
    tmp[t] = v; __syncthreads();
    for (int s = 1; s < 1024; s <<= 1) {
        int a = (t >= s) ? tmp[t - s] : 0;
        __syncthreads(); tmp[t] += a; __syncthreads();
    }
    if (idx < N) coff[idx] = tmp[t] - v;
    if (t == 1023) part[blockIdx.x] = tmp[1023];
}

__global__ __launch_bounds__(1024) void k_scan_b(int* __restrict__ part,
                                                 int* __restrict__ coff, int nblk, int N) {
    __shared__ int tmp[1024];
    const int t = threadIdx.x;
    const int v = (t < nblk) ? part[t] : 0;
    tmp[t] = v; __syncthreads();
    for (int s = 1; s < 1024; s <<= 1) {
        int a = (t >= s) ? tmp[t - s] : 0;
        __syncthreads(); tmp[t] += a; __syncthreads();
    }
    if (t < nblk) part[t] = tmp[t] - v;
    if (t == 1023) coff[N] = tmp[1023];
}

__global__ __launch_bounds__(1024) void k_scan_c(int* __restrict__ coff,
                                                 const int* __restrict__ part, int N) {
    const int idx = blockIdx.x * 1024 + threadIdx.x;
    if (idx < N) coff[idx] += part[blockIdx.x];
}

__global__ void k_scatter(const void* __restrict__ ei, const int* __restrict__ flags,
                          const int* __restrict__ coff, int* __restrict__ cpos,
                          int* __restrict__ csrc, int E, int N) {
    const int f64 = flags[1];
    const int EP = E + N;
    for (int e = blockIdx.x * blockDim.x + threadIdx.x; e < EP; e += gridDim.x * blockDim.x) {
        int src, dst;
        if (e < E) { src = edge_at(ei, f64, e); dst = edge_at(ei, f64, (long long)E + e); }
        else       { src = dst = e - E; }
        const int p = atomicAdd(&cpos[dst], 1);
        csrc[coff[dst] + p] = src;
    }
}

// ---------- split-precision MFMA GEMM ----------
// Y[n, 0:128) f32 = X[n,0:128] @ W[0:128, wc0..wc0+128)
// hi/lo bf16 planes, D = Ah*Bh + Ah*Bl + Al*Bh  (~f32 precision)
// block: 64 rows x 128 cols, 4 waves (wave w -> cols w*32..w*32+32), K staged in 2x64
template <bool XRAW>
__global__ __launch_bounds__(256) void k_gemm(const void* __restrict__ Xv,
                                              const void* __restrict__ Wv,
                                              float* __restrict__ Y,
                                              const int* __restrict__ flags,
                                              int N, int wstride, int wcolBase) {
    __shared__ __align__(16) unsigned short Ah[64][72],  Al[64][72];
    __shared__ __align__(16) unsigned short Bh[128][72], Bl[128][72];
    const int bf   = flags[0];
    const int t    = threadIdx.x;
    const int row0 = blockIdx.x * 64;
    const int wv   = t >> 6;
    const int lane = t & 63;
    const int quad = lane >> 4;
    const int l16  = lane & 15;

    floatx4 acc[4][2];
#pragma unroll
    for (int mt = 0; mt < 4; ++mt)
#pragma unroll
        for (int nt = 0; nt < 2; ++nt) acc[mt][nt] = (floatx4){0.f, 0.f, 0.f, 0.f};

    for (int kb = 0; kb < 2; ++kb) {
        // stage A chunk: 64 rows x 64 k  (1024 float4-groups, 4 iters)
#pragma unroll
        for (int it = 0; it < 4; ++it) {
            const int id = it * 256 + t;
            const int r  = id >> 4;
            const int c  = (id & 15) * 4;
            const int gr = row0 + r;
            ushort4 h4 = make_ushort4(0, 0, 0, 0), l4 = make_ushort4(0, 0, 0, 0);
            if (gr < N) {
                if (XRAW && bf) {
                    h4 = *(const ushort4*)&((const unsigned short*)Xv)[(size_t)gr * 128 + kb * 64 + c];
                } else {
                    const float4 f = *(const float4*)&((const float*)Xv)[(size_t)gr * 128 + kb * 64 + c];
                    split2(f.x, h4.x, l4.x); split2(f.y, h4.y, l4.y);
                    split2(f.z, h4.z, l4.z); split2(f.w, h4.w, l4.w);
                }
            }
            *(ushort4*)&Ah[r][c] = h4;
            *(ushort4*)&Al[r][c] = l4;
        }
        // stage B chunk (transposed): 64 k x 128 cols (2048 float4-groups, 8 iters)
#pragma unroll
        for (int it = 0; it < 8; ++it) {
            const int id = it * 256 + t;
            const int k  = id >> 5;
            const int c  = (id & 31) * 4;
            const size_t g = (size_t)(kb * 64 + k) * wstride + wcolBase + c;
            if (bf) {
                const ushort4 u = *(const ushort4*)&((const unsigned short*)Wv)[g];
                Bh[c][k] = u.x; Bh[c + 1][k] = u.y; Bh[c + 2][k] = u.z; Bh[c + 3][k] = u.w;
                Bl[c][k] = 0;   Bl[c + 1][k] = 0;   Bl[c + 2][k] = 0;   Bl[c + 3][k] = 0;
            } else {
                const float4 f = *(const float4*)&((const float*)Wv)[g];
                unsigned short h0, l0, h1, l1, h2, l2, h3, l3;
                split2(f.x, h0, l0); split2(f.y, h1, l1);
                split2(f.z, h2, l2); split2(f.w, h3, l3);
                Bh[c][k] = h0; Bh[c + 1][k] = h1; Bh[c + 2][k] = h2; Bh[c + 3][k] = h3;
                Bl[c][k] = l0; Bl[c + 1][k] = l1; Bl[c + 2][k] = l2; Bl[c + 3][k] = l3;
            }
        }
        __syncthreads();

#pragma unroll
        for (int ks = 0; ks < 2; ++ks) {
            const int ko = ks * 32 + quad * 8;
            bf16x8 ah[4], al[4], bh[2], bl[2];
#pragma unroll
            for (int mt = 0; mt < 4; ++mt) {
                ah[mt] = *(const bf16x8*)&Ah[mt * 16 + l16][ko];
                al[mt] = *(const bf16x8*)&Al[mt * 16 + l16][ko];
            }
#pragma unroll
            for (int nt = 0; nt < 2; ++nt) {
                bh[nt] = *(const bf16x8*)&Bh[wv * 32 + nt * 16 + l16][ko];
                bl[nt] = *(const bf16x8*)&Bl[wv * 32 + nt * 16 + l16][ko];
            }
#pragma unroll
            for (int mt = 0; mt < 4; ++mt)
#pragma unroll
                for (int nt = 0; nt < 2; ++nt) {
                    acc[mt][nt] = __builtin_amdgcn_mfma_f32_16x16x32_bf16(ah[mt], bh[nt], acc[mt][nt], 0, 0, 0);
                    acc[mt][nt] = __builtin_amdgcn_mfma_f32_16x16x32_bf16(ah[mt], bl[nt], acc[mt][nt], 0, 0, 0);
                    acc[mt][nt] = __builtin_amdgcn_mfma_f32_16x16x32_bf16(al[mt], bh[nt], acc[mt][nt], 0, 0, 0);
                }
        }
        __syncthreads();
    }

    // store f32; C/D layout: col=lane&15, row=quad*4+reg
#pragma unroll
    for (int mt = 0; mt < 4; ++mt) {
        const int row = row0 + mt * 16 + quad * 4;
#pragma unroll
        for (int nt = 0; nt < 2; ++nt) {
            const int col = wv * 32 + nt * 16 + l16;
#pragma unroll
            for (int r = 0; r < 4; ++r)
                if (row + r < N) Y[(size_t)(row + r) * 128 + col] = acc[mt][nt][r];
        }
    }
}

// ---------- attention scores (H f32) ----------
template <int C>
__global__ __launch_bounds__(256) void k_scores(const float* __restrict__ Hf,
                                                const void* __restrict__ a_src,
                                                const void* __restrict__ a_dst,
                                                int aoff,
                                                const int* __restrict__ flags,
                                                float* __restrict__ ssrc, float* __restrict__ sdst,
                                                int N) {
    const int bf   = flags[0];
    const int wave = blockIdx.x * (blockDim.x >> 6) + (threadIdx.x >> 6);
    const int lane = threadIdx.x & 63;
    if (wave >= N) return;
    const float as0 = ldx(a_src, aoff + lane, bf);
    const float as1 = ldx(a_src, aoff + lane + 64, bf);
    const float ad0 = ldx(a_dst, aoff + lane, bf);
    const float ad1 = ldx(a_dst, aoff + lane + 64, bf);
    const float h0 = Hf[(size_t)wave * 128 + lane];
    const float h1 = Hf[(size_t)wave * 128 + lane + 64];
    float ps0 = h0 * as0, ps1 = h1 * as1;
    float pd0 = h0 * ad0, pd1 = h1 * ad1;
    if (C == 32) {
#pragma unroll
        for (int mk = 1; mk <= 16; mk <<= 1) {
            ps0 += __shfl_xor(ps0, mk); ps1 += __shfl_xor(ps1, mk);
            pd0 += __shfl_xor(pd0, mk); pd1 += __shfl_xor(pd1, mk);
        }
        if (lane == 0)  { ssrc[wave*4+0]=ps0; ssrc[wave*4+2]=ps1; sdst[wave*4+0]=pd0; sdst[wave*4+2]=pd1; }
        if (lane == 32) { ssrc[wave*4+1]=ps0; ssrc[wave*4+3]=ps1; sdst[wave*4+1]=pd0; sdst[wave*4+3]=pd1; }
    } else {
        float ps = ps0 + ps1, pd = pd0 + pd1;
#pragma unroll
        for (int mk = 1; mk <= 32; mk <<= 1) { ps += __shfl_xor(ps, mk); pd += __shfl_xor(pd, mk); }
        if (lane == 0) { ssrc[wave] = ps; sdst[wave] = pd; }
    }
}

// ---------- softmax + aggregation; one wave per node; lane owns channels 2*lane, 2*lane+1 ----------
template <int NUMS, int MODE>
__global__ __launch_bounds__(256) void k_agg(const int* __restrict__ coff,
                                             const int* __restrict__ csrc,
                                             const float* __restrict__ ssrc,
                                             const float* __restrict__ sdst,
                                             const float* __restrict__ Hf,
                                             const void* __restrict__ bias,
                                             const void* __restrict__ resid,
                                             const int* __restrict__ flags,
                                             float* __restrict__ out, int N) {
    const int bf   = flags[0];
    const int n    = blockIdx.x * (blockDim.x >> 6) + (threadIdx.x >> 6);
    const int lane = threadIdx.x & 63;
    if (n >= N) return;
    const int beg = coff[n], end = coff[n + 1];
    const int deg = end - beg;
    const int myh = (NUMS == 4) ? (lane >> 4) : 0;

    float sd[NUMS];
#pragma unroll
    for (int h = 0; h < NUMS; ++h) sd[h] = sdst[n * NUMS + h];

    float acc0 = 0.f, acc1 = 0.f;

    if (deg <= 64) {
        const bool act = lane < deg;
        int myS = 0;
        float v[NUMS];
#pragma unroll
        for (int h = 0; h < NUMS; ++h) v[h] = -1e30f;
        if (act) {
            myS = csrc[beg + lane];
            if (NUMS == 4) {
                const float4 sp = *(const float4*)&ssrc[(size_t)myS * 4];
                const float s4[4] = { sp.x, sp.y, sp.z, sp.w };
#pragma unroll
                for (int h = 0; h < 4; ++h) {
                    float tv = s4[h] + sd[h];
                    v[h] = tv >= 0.f ? tv : NEG_SLOPE * tv;
                }
            } else {
                float tv = ssrc[myS] + sd[0];
                v[0] = tv >= 0.f ? tv : NEG_SLOPE * tv;
            }
        }
        float m[NUMS];
#pragma unroll
        for (int h = 0; h < NUMS; ++h) m[h] = v[h];
#pragma unroll
        for (int mk = 1; mk <= 32; mk <<= 1)
#pragma unroll
            for (int h = 0; h < NUMS; ++h) m[h] = fmaxf(m[h], __shfl_xor(m[h], mk));
        float w[NUMS];
#pragma unroll
        for (int h = 0; h < NUMS; ++h) w[h] = act ? expf(v[h] - m[h]) : 0.f;
        float z[NUMS];
#pragma unroll
        for (int h = 0; h < NUMS; ++h) z[h] = w[h];
#pragma unroll
        for (int mk = 1; mk <= 32; mk <<= 1)
#pragma unroll
            for (int h = 0; h < NUMS; ++h) z[h] += __shfl_xor(z[h], mk);
#pragma unroll
        for (int h = 0; h < NUMS; ++h) w[h] *= 1.f / (z[h] + 1e-16f);

        for (int e = 0; e < deg; ++e) {
            const int s = __shfl(myS, e);
            float wA;
            if (NUMS == 4) {
                const float w0 = __shfl(w[0], e), w1 = __shfl(w[1], e);
                const float w2 = __shfl(w[2], e), w3 = __shfl(w[3], e);
                const float wlo = (lane & 16) ? w1 : w0;
                const float whi = (lane & 16) ? w3 : w2;
                wA = (lane & 32) ? whi : wlo;
            } else {
                wA = __shfl(w[0], e);
            }
            const float2 u = *(const float2*)&Hf[(size_t)s * 128 + 2 * lane];
            acc0 = fmaf(wA, u.x, acc0);
            acc1 = fmaf(wA, u.y, acc1);
        }
    } else {
        float m[NUMS];
#pragma unroll
        for (int h = 0; h < NUMS; ++h) m[h] = -1e30f;
        for (int e = beg + lane; e < end; e += 64) {
            const int s = csrc[e];
#pragma unroll
            for (int h = 0; h < NUMS; ++h) {
                float tv = ssrc[(size_t)s * NUMS + h] + sd[h];
                tv = tv >= 0.f ? tv : NEG_SLOPE * tv;
                m[h] = fmaxf(m[h], tv);
            }
        }
#pragma unroll
        for (int mk = 1; mk <= 32; mk <<= 1)
#pragma unroll
            for (int h = 0; h < NUMS; ++h) m[h] = fmaxf(m[h], __shfl_xor(m[h], mk));
        float z[NUMS] = {};
        for (int e = beg + lane; e < end; e += 64) {
            const int s = csrc[e];
#pragma unroll
            for (int h = 0; h < NUMS; ++h) {
                float tv = ssrc[(size_t)s * NUMS + h] + sd[h];
                tv = tv >= 0.f ? tv : NEG_SLOPE * tv;
                z[h] += expf(tv - m[h]);
            }
        }
#pragma unroll
        for (int mk = 1; mk <= 32; mk <<= 1)
#pragma unroll
            for (int h = 0; h < NUMS; ++h) z[h] += __shfl_xor(z[h], mk);
        const float mh  = m[myh];
        const float ivh = 1.f / (z[myh] + 1e-16f);
        const float sdh = sd[myh];
        for (int e = beg; e < end; ++e) {
            const int s = csrc[e];
            float tv = ssrc[(size_t)s * NUMS + myh] + sdh;
            tv = tv >= 0.f ? tv : NEG_SLOPE * tv;
            const float wA = expf(tv - mh) * ivh;
            const float2 u = *(const float2*)&Hf[(size_t)s * 128 + 2 * lane];
            acc0 = fmaf(wA, u.x, acc0);
            acc1 = fmaf(wA, u.y, acc1);
        }
    }

    const int o2 = n * 128 + 2 * lane;
    if (MODE == 2) {
        float2 cur = *(float2*)&out[o2];
        cur.x += acc0; cur.y += acc1;
        *(float2*)&out[o2] = cur;
    } else {
        const float b0 = ldx(bias, 2 * lane, bf), b1 = ldx(bias, 2 * lane + 1, bf);
        float r0, r1;
        if (MODE == 0) { r0 = ldx(resid, o2, bf); r1 = ldx(resid, o2 + 1, bf); }
        else           { r0 = ((const float*)resid)[o2]; r1 = ((const float*)resid)[o2 + 1]; }
        const float v0 = acc0 + b0 + r0;
        const float v1 = acc1 + b1 + r1;
        float2 o;
        o.x = v0 > 0.f ? v0 : expm1f(v0);
        o.y = v1 > 0.f ? v1 : expm1f(v1);
        *(float2*)&out[o2] = o;
    }
}

// ---------- final: out = cast(acc/4 + b3 + x2) ----------
__global__ void k_final(const float* __restrict__ acc, const void* __restrict__ b3,
                        const float* __restrict__ x2, void* __restrict__ out,
                        const int* __restrict__ flags, int total) {
    const int bf = flags[0];
    for (int i = blockIdx.x * blockDim.x + threadIdx.x; i < total; i += gridDim.x * blockDim.x) {
        const int c = i & 127;
        const float v = acc[i] * 0.25f + ldx(b3, c, bf) + x2[i];
        if (bf) ((unsigned short*)out)[i] = f2us(v);
        else    ((float*)out)[i] = v;
    }
}

extern "C" void kernel_launch(void* const* d_in, const int* in_sizes, int n_in,
                              void* d_out, int out_size, void* d_ws, size_t ws_size,
                              hipStream_t stream) {
    const int N  = in_sizes[0] / 128;
    const int E  = in_sizes[1] / 2;
    const int EP = E + N;

    const void* x   = d_in[0];
    const void* ei  = d_in[1];
    const void* W1  = d_in[2];
    const void* as1 = d_in[3];
    const void* ad1 = d_in[4];
    const void* b1  = d_in[5];
    const void* W2  = d_in[6];
    const void* as2 = d_in[7];
    const void* ad2 = d_in[8];
    const void* b2  = d_in[9];
    const void* W3  = d_in[10];
    const void* as3 = d_in[11];
    const void* ad3 = d_in[12];
    const void* b3  = d_in[13];

    char* p = (char*)d_ws;
    auto alloc = [&](size_t bytes) { char* r = p; p += (bytes + 255) & ~(size_t)255; return r; };
    int*   flags = (int*)alloc(8);
    int*   deg   = (int*)alloc((size_t)(N + 1) * 4);
    int*   coff  = (int*)alloc((size_t)(N + 1) * 4);
    int*   cpos  = (int*)alloc((size_t)N * 4);
    int*   part  = (int*)alloc(4096);
    int*   csrc  = (int*)alloc((size_t)EP * 4);
    float* hbuf  = (float*)alloc((size_t)N * 128 * 4);
    float* x1b   = (float*)alloc((size_t)N * 128 * 4);
    float* x2b   = (float*)alloc((size_t)N * 128 * 4);
    float* accb  = (float*)alloc((size_t)N * 128 * 4);
    float* ssrc  = (float*)alloc((size_t)N * 4 * 4);
    float* sdst  = (float*)alloc((size_t)N * 4 * 4);

    hipMemsetAsync(deg,  0, (size_t)(N + 1) * 4, stream);
    hipMemsetAsync(cpos, 0, (size_t)N * 4, stream);
    hipMemsetAsync(accb, 0, (size_t)N * 128 * 4, stream);

    k_detect<<<1, 64, 0, stream>>>((const unsigned short*)x, (const unsigned int*)ei, flags);

    const int egrid = (EP + 255) / 256;
    const int nblk  = (N + 1023) / 1024;
    k_hist<<<egrid, 256, 0, stream>>>(ei, flags, deg, E, N);
    k_scan_a<<<nblk, 1024, 0, stream>>>(deg, coff, part, N);
    k_scan_b<<<1, 1024, 0, stream>>>(part, coff, nblk, N);
    k_scan_c<<<nblk, 1024, 0, stream>>>(coff, part, N);
    k_scatter<<<egrid, 256, 0, stream>>>(ei, flags, coff, cpos, csrc, E, N);

    const int ggrid = (N + 63) / 64;
    const int ngrid = (N + 3) / 4;

    // ---- layer 1
    k_gemm<true ><<<ggrid, 256, 0, stream>>>(x,   W1, hbuf, flags, N, 128, 0);
    k_scores<32><<<ngrid, 256, 0, stream>>>(hbuf, as1, ad1, 0, flags, ssrc, sdst, N);
    k_agg<4, 0><<<ngrid, 256, 0, stream>>>(coff, csrc, ssrc, sdst, hbuf, b1, x,   flags, x1b, N);

    // ---- layer 2
    k_gemm<false><<<ggrid, 256, 0, stream>>>(x1b, W2, hbuf, flags, N, 128, 0);
    k_scores<32><<<ngrid, 256, 0, stream>>>(hbuf, as2, ad2, 0, flags, ssrc, sdst, N);
    k_agg<4, 1><<<ngrid, 256, 0, stream>>>(coff, csrc, ssrc, sdst, hbuf, b2, x1b, flags, x2b, N);

    // ---- layer 3: mean over 4 heads
    for (int h = 0; h < 4; ++h) {
        k_gemm<false><<<ggrid, 256, 0, stream>>>(x2b, W3, hbuf, flags, N, 512, h * 128);
        k_scores<128><<<ngrid, 256, 0, stream>>>(hbuf, as3, ad3, h * 128, flags, ssrc, sdst, N);
        k_agg<1, 2><<<ngrid, 256, 0, stream>>>(coff, csrc, ssrc, sdst, hbuf,
                                               nullptr, nullptr, flags, accb, N);
    }

    k_final<<<2048, 256, 0, stream>>>(accb, b3, x2b, d_out, flags, N * 128);
}

// Round 5
// 1207.539 us; speedup vs baseline: 1.8531x; 1.1526x over previous
//
#include <hip/hip_runtime.h>
#include <hip/hip_bf16.h>
#include <cstdint>

#define NEG_SLOPE 0.2f

typedef __bf16 bf16x8 __attribute__((ext_vector_type(8)));
typedef float  floatx4 __attribute__((ext_vector_type(4)));

// ---------- bf16 helpers ----------
__device__ __forceinline__ float us2f(unsigned short u) {
    union { unsigned int i; float f; } c; c.i = ((unsigned int)u) << 16; return c.f;
}
__device__ __forceinline__ unsigned short f2us(float f) {
    union { float f; unsigned int i; } c; c.f = f;
    unsigned int x = c.i;
    unsigned int r = (x + 0x7fffu + ((x >> 16) & 1u)) >> 16;   // RNE
    return (unsigned short)r;
}
__device__ __forceinline__ float ldx(const void* p, int i, int bf) {
    return bf ? us2f(((const unsigned short*)p)[i]) : ((const float*)p)[i];
}
__device__ __forceinline__ void split2(float f, unsigned short& h, unsigned short& l) {
    h = f2us(f);
    l = f2us(f - us2f(h));
}

// ---------- runtime dtype probes ----------
__global__ void k_detect(const unsigned short* __restrict__ x16,
                         const unsigned int* __restrict__ ei,
                         int* __restrict__ flags) {
    if (threadIdx.x == 0 && blockIdx.x == 0) {
        int cnt = 0;
        for (int i = 0; i < 1024; ++i) {
            const unsigned short u = x16[2 * i];
            const int e = (u >> 7) & 0xFF;
            if (e < 100 || e > 160) ++cnt;
        }
        flags[0] = (cnt < 256) ? 1 : 0;      // bf16?
        int is64 = 1;
        for (int i = 0; i < 64; ++i)
            if (ei[2 * i + 1] != 0u) { is64 = 0; break; }
        flags[1] = is64;                      // int64?
    }
}

__device__ __forceinline__ int edge_at(const void* ei, int f64, long long idx) {
    if (f64) return (int)((const long long*)ei)[idx];
    return ((const int*)ei)[idx];
}

// ---------- CSR build ----------
__global__ void k_hist(const void* __restrict__ ei, const int* __restrict__ flags,
                       int* __restrict__ deg, int E, int N) {
    const int f64 = flags[1];
    const int EP = E + N;
    for (int e = blockIdx.x * blockDim.x + threadIdx.x; e < EP; e += gridDim.x * blockDim.x) {
        int dst = (e < E) ? edge_at(ei, f64, (long long)E + e) : (e - E);
        atomicAdd(&deg[dst], 1);
    }
}

__global__ __launch_bounds__(1024) void k_scan_a(const int* __restrict__ deg,
                                                 int* __restrict__ coff,
                                                 int* __restrict__ part, int N) {
    __shared__ int tmp[1024];
    const int t = threadIdx.x, idx = blockIdx.x * 1024 + t;
    const int v = (idx < N) ? deg[idx] : 0;
    tmp[t] = v; __syncthreads();
    for (int s = 1; s < 1024; s <<= 1) {
        int a = (t >= s) ? tmp[t - s] : 0;
        __syncthreads(); tmp[t] += a; __syncthreads();
    }
    if (idx < N) coff[idx] = tmp[t] - v;
    if (t == 1023) part[blockIdx.x] = tmp[1023];
}

__global__ __launch_bounds__(1024) void k_scan_b(int* __restrict__ part,
                                                 int* __restrict__ coff, int nblk, int N) {
    __shared__ int tmp[1024];
    const int t = threadIdx.x;
    const int v = (t < nblk) ? part[t] : 0;
    tmp[t] = v; __syncthreads();
    for (int s = 1; s < 1024; s <<= 1) {
        int a = (t >= s) ? tmp[t - s] : 0;
        __syncthreads(); tmp[t] += a; __syncthreads();
    }
    if (t < nblk) part[t] = tmp[t] - v;
    if (t == 1023) coff[N] = tmp[1023];
}

__global__ __launch_bounds__(1024) void k_scan_c(int* __restrict__ coff,
                                                 const int* __restrict__ part, int N) {
    const int idx = blockIdx.x * 1024 + threadIdx.x;
    if (idx < N) coff[idx] += part[blockIdx.x];
}

__global__ void k_scatter(const void* __restrict__ ei, const int* __restrict__ flags,
                          const int* __restrict__ coff, int* __restrict__ cpos,
                          int* __restrict__ csrc, int E, int N) {
    const int f64 = flags[1];
    const int EP = E + N;
    for (int e = blockIdx.x * blockDim.x + threadIdx.x; e < EP; e += gridDim.x * blockDim.x) {
        int src, dst;
        if (e < E) { src = edge_at(ei, f64, e); dst = edge_at(ei, f64, (long long)E + e); }
        else       { src = dst = e - E; }
        const int p = atomicAdd(&cpos[dst], 1);
        csrc[coff[dst] + p] = src;
    }
}

// ---------- split-precision MFMA GEMM, dual-store f32 + bf16 ----------
template <bool XRAW>
__global__ __launch_bounds__(256) void k_gemm(const void* __restrict__ Xv,
                                              const void* __restrict__ Wv,
                                              float* __restrict__ Y,
                                              unsigned short* __restrict__ Y16,
                                              const int* __restrict__ flags,
                                              int N, int wstride, int wcolBase) {
    __shared__ __align__(16) unsigned short Ah[64][72],  Al[64][72];
    __shared__ __align__(16) unsigned short Bh[128][72], Bl[128][72];
    const int bf   = flags[0];
    const int t    = threadIdx.x;
    const int row0 = blockIdx.x * 64;
    const int wv   = t >> 6;
    const int lane = t & 63;
    const int quad = lane >> 4;
    const int l16  = lane & 15;

    floatx4 acc[4][2];
#pragma unroll
    for (int mt = 0; mt < 4; ++mt)
#pragma unroll
        for (int nt = 0; nt < 2; ++nt) acc[mt][nt] = (floatx4){0.f, 0.f, 0.f, 0.f};

    for (int kb = 0; kb < 2; ++kb) {
#pragma unroll
        for (int it = 0; it < 4; ++it) {
            const int id = it * 256 + t;
            const int r  = id >> 4;
            const int c  = (id & 15) * 4;
            const int gr = row0 + r;
            ushort4 h4 = make_ushort4(0, 0, 0, 0), l4 = make_ushort4(0, 0, 0, 0);
            if (gr < N) {
                if (XRAW && bf) {
                    h4 = *(const ushort4*)&((const unsigned short*)Xv)[(size_t)gr * 128 + kb * 64 + c];
                } else {
                    const float4 f = *(const float4*)&((const float*)Xv)[(size_t)gr * 128 + kb * 64 + c];
                    split2(f.x, h4.x, l4.x); split2(f.y, h4.y, l4.y);
                    split2(f.z, h4.z, l4.z); split2(f.w, h4.w, l4.w);
                }
            }
            *(ushort4*)&Ah[r][c] = h4;
            *(ushort4*)&Al[r][c] = l4;
        }
#pragma unroll
        for (int it = 0; it < 8; ++it) {
            const int id = it * 256 + t;
            const int k  = id >> 5;
            const int c  = (id & 31) * 4;
            const size_t g = (size_t)(kb * 64 + k) * wstride + wcolBase + c;
            if (bf) {
                const ushort4 u = *(const ushort4*)&((const unsigned short*)Wv)[g];
                Bh[c][k] = u.x; Bh[c + 1][k] = u.y; Bh[c + 2][k] = u.z; Bh[c + 3][k] = u.w;
                Bl[c][k] = 0;   Bl[c + 1][k] = 0;   Bl[c + 2][k] = 0;   Bl[c + 3][k] = 0;
            } else {
                const float4 f = *(const float4*)&((const float*)Wv)[g];
                unsigned short h0, l0, h1, l1, h2, l2, h3, l3;
                split2(f.x, h0, l0); split2(f.y, h1, l1);
                split2(f.z, h2, l2); split2(f.w, h3, l3);
                Bh[c][k] = h0; Bh[c + 1][k] = h1; Bh[c + 2][k] = h2; Bh[c + 3][k] = h3;
                Bl[c][k] = l0; Bl[c + 1][k] = l1; Bl[c + 2][k] = l2; Bl[c + 3][k] = l3;
            }
        }
        __syncthreads();

#pragma unroll
        for (int ks = 0; ks < 2; ++ks) {
            const int ko = ks * 32 + quad * 8;
            bf16x8 ah[4], al[4], bh[2], bl[2];
#pragma unroll
            for (int mt = 0; mt < 4; ++mt) {
                ah[mt] = *(const bf16x8*)&Ah[mt * 16 + l16][ko];
                al[mt] = *(const bf16x8*)&Al[mt * 16 + l16][ko];
            }
#pragma unroll
            for (int nt = 0; nt < 2; ++nt) {
                bh[nt] = *(const bf16x8*)&Bh[wv * 32 + nt * 16 + l16][ko];
                bl[nt] = *(const bf16x8*)&Bl[wv * 32 + nt * 16 + l16][ko];
            }
#pragma unroll
            for (int mt = 0; mt < 4; ++mt)
#pragma unroll
                for (int nt = 0; nt < 2; ++nt) {
                    acc[mt][nt] = __builtin_amdgcn_mfma_f32_16x16x32_bf16(ah[mt], bh[nt], acc[mt][nt], 0, 0, 0);
                    acc[mt][nt] = __builtin_amdgcn_mfma_f32_16x16x32_bf16(ah[mt], bl[nt], acc[mt][nt], 0, 0, 0);
                    acc[mt][nt] = __builtin_amdgcn_mfma_f32_16x16x32_bf16(al[mt], bh[nt], acc[mt][nt], 0, 0, 0);
                }
        }
        __syncthreads();
    }

#pragma unroll
    for (int mt = 0; mt < 4; ++mt) {
        const int row = row0 + mt * 16 + quad * 4;
#pragma unroll
        for (int nt = 0; nt < 2; ++nt) {
            const int col = wv * 32 + nt * 16 + l16;
#pragma unroll
            for (int r = 0; r < 4; ++r)
                if (row + r < N) {
                    const size_t o = (size_t)(row + r) * 128 + col;
                    Y[o]   = acc[mt][nt][r];
                    Y16[o] = f2us(acc[mt][nt][r]);
                }
        }
    }
}

// ---------- attention scores (H f32) ----------
template <int C>
__global__ __launch_bounds__(256) void k_scores(const float* __restrict__ Hf,
                                                const void* __restrict__ a_src,
                                                const void* __restrict__ a_dst,
                                                int aoff,
                                                const int* __restrict__ flags,
                                                float* __restrict__ ssrc, float* __restrict__ sdst,
                                                int N) {
    const int bf   = flags[0];
    const int wave = blockIdx.x * (blockDim.x >> 6) + (threadIdx.x >> 6);
    const int lane = threadIdx.x & 63;
    if (wave >= N) return;
    const float as0 = ldx(a_src, aoff + lane, bf);
    const float as1 = ldx(a_src, aoff + lane + 64, bf);
    const float ad0 = ldx(a_dst, aoff + lane, bf);
    const float ad1 = ldx(a_dst, aoff + lane + 64, bf);
    const float h0 = Hf[(size_t)wave * 128 + lane];
    const float h1 = Hf[(size_t)wave * 128 + lane + 64];
    float ps0 = h0 * as0, ps1 = h1 * as1;
    float pd0 = h0 * ad0, pd1 = h1 * ad1;
    if (C == 32) {
#pragma unroll
        for (int mk = 1; mk <= 16; mk <<= 1) {
            ps0 += __shfl_xor(ps0, mk); ps1 += __shfl_xor(ps1, mk);
            pd0 += __shfl_xor(pd0, mk); pd1 += __shfl_xor(pd1, mk);
        }
        if (lane == 0)  { ssrc[wave*4+0]=ps0; ssrc[wave*4+2]=ps1; sdst[wave*4+0]=pd0; sdst[wave*4+2]=pd1; }
        if (lane == 32) { ssrc[wave*4+1]=ps0; ssrc[wave*4+3]=ps1; sdst[wave*4+1]=pd0; sdst[wave*4+3]=pd1; }
    } else {
        float ps = ps0 + ps1, pd = pd0 + pd1;
#pragma unroll
        for (int mk = 1; mk <= 32; mk <<= 1) { ps += __shfl_xor(ps, mk); pd += __shfl_xor(pd, mk); }
        if (lane == 0) { ssrc[wave] = ps; sdst[wave] = pd; }
    }
}

// ---------- softmax + aggregation; one wave per node; bf16 gather ----------
// MODE 0: out = elu(acc + bias + raw resid)     out f32
// MODE 1: out = elu(acc + bias + f32 resid)     out f32
// MODE 2: out += acc                            out f32
// MODE 3: final = cast((accIn+acc)*0.25 + bias + f32 resid)  out = d_out
template <int NUMS, int MODE>
__global__ __launch_bounds__(256) void k_agg(const int* __restrict__ coff,
                                             const int* __restrict__ csrc,
                                             const float* __restrict__ ssrc,
                                             const float* __restrict__ sdst,
                                             const unsigned short* __restrict__ H16,
                                             const void* __restrict__ bias,
                                             const void* __restrict__ resid,
                                             const float* __restrict__ accIn,
                                             const int* __restrict__ flags,
                                             void* __restrict__ out, int N) {
    __shared__ int   sS[4][64];
    __shared__ float wS[4][64 * NUMS];
    const int bf   = flags[0];
    const int wv   = threadIdx.x >> 6;
    const int lane = threadIdx.x & 63;
    const int n0   = blockIdx.x * 4 + wv;
    const bool nact = n0 < N;
    const int n    = nact ? n0 : (N - 1);
    const int beg = coff[n], end = coff[n + 1];
    const int deg = end - beg;
    const int myh = (NUMS == 4) ? (lane >> 4) : 0;

    float sd[NUMS];
#pragma unroll
    for (int h = 0; h < NUMS; ++h) sd[h] = sdst[n * NUMS + h];

    const bool fast = (deg <= 64);
    float m[NUMS], z[NUMS];

    if (fast) {
        const bool act = lane < deg;
        int myS = 0;
        float v[NUMS];
#pragma unroll
        for (int h = 0; h < NUMS; ++h) v[h] = -1e30f;
        if (act) {
            myS = csrc[beg + lane];
            if (NUMS == 4) {
                const float4 sp = *(const float4*)&ssrc[(size_t)myS * 4];
                const float s4[4] = { sp.x, sp.y, sp.z, sp.w };
#pragma unroll
                for (int h = 0; h < 4; ++h) {
                    float tv = s4[h] + sd[h];
                    v[h] = tv >= 0.f ? tv : NEG_SLOPE * tv;
                }
            } else {
                float tv = ssrc[myS] + sd[0];
                v[0] = tv >= 0.f ? tv : NEG_SLOPE * tv;
            }
        }
#pragma unroll
        for (int h = 0; h < NUMS; ++h) m[h] = v[h];
#pragma unroll
        for (int mk = 1; mk <= 32; mk <<= 1)
#pragma unroll
            for (int h = 0; h < NUMS; ++h) m[h] = fmaxf(m[h], __shfl_xor(m[h], mk));
        float w[NUMS];
#pragma unroll
        for (int h = 0; h < NUMS; ++h) w[h] = act ? expf(v[h] - m[h]) : 0.f;
#pragma unroll
        for (int h = 0; h < NUMS; ++h) z[h] = w[h];
#pragma unroll
        for (int mk = 1; mk <= 32; mk <<= 1)
#pragma unroll
            for (int h = 0; h < NUMS; ++h) z[h] += __shfl_xor(z[h], mk);
        if (act) {
            sS[wv][lane] = myS;
#pragma unroll
            for (int h = 0; h < NUMS; ++h)
                wS[wv][lane * NUMS + h] = w[h] / (z[h] + 1e-16f);
        }
    } else {
        // streaming 3-pass for deg > 64 (rare)
#pragma unroll
        for (int h = 0; h < NUMS; ++h) m[h] = -1e30f;
        for (int e = beg + lane; e < end; e += 64) {
            const int s = csrc[e];
#pragma unroll
            for (int h = 0; h < NUMS; ++h) {
                float tv = ssrc[(size_t)s * NUMS + h] + sd[h];
                tv = tv >= 0.f ? tv : NEG_SLOPE * tv;
                m[h] = fmaxf(m[h], tv);
            }
        }
#pragma unroll
        for (int mk = 1; mk <= 32; mk <<= 1)
#pragma unroll
            for (int h = 0; h < NUMS; ++h) m[h] = fmaxf(m[h], __shfl_xor(m[h], mk));
#pragma unroll
        for (int h = 0; h < NUMS; ++h) z[h] = 0.f;
        for (int e = beg + lane; e < end; e += 64) {
            const int s = csrc[e];
#pragma unroll
            for (int h = 0; h < NUMS; ++h) {
                float tv = ssrc[(size_t)s * NUMS + h] + sd[h];
                tv = tv >= 0.f ? tv : NEG_SLOPE * tv;
                z[h] += expf(tv - m[h]);
            }
        }
#pragma unroll
        for (int mk = 1; mk <= 32; mk <<= 1)
#pragma unroll
            for (int h = 0; h < NUMS; ++h) z[h] += __shfl_xor(z[h], mk);
    }

    __syncthreads();

    float acc0 = 0.f, acc1 = 0.f;
    if (fast) {
        for (int e = 0; e < deg; ++e) {
            const int   s  = sS[wv][e];
            const float wA = wS[wv][e * NUMS + myh];
            const unsigned int u = *(const unsigned int*)&H16[(size_t)s * 128 + 2 * lane];
            union { unsigned int i; float f; } lo, hi;
            lo.i = u << 16; hi.i = u & 0xffff0000u;
            acc0 = fmaf(wA, lo.f, acc0);
            acc1 = fmaf(wA, hi.f, acc1);
        }
    } else {
        const float mh  = m[myh];
        const float ivh = 1.f / (z[myh] + 1e-16f);
        const float sdh = sd[myh];
        for (int e = beg; e < end; ++e) {
            const int s = csrc[e];
            float tv = ssrc[(size_t)s * NUMS + myh] + sdh;
            tv = tv >= 0.f ? tv : NEG_SLOPE * tv;
            const float wA = expf(tv - mh) * ivh;
            const unsigned int u = *(const unsigned int*)&H16[(size_t)s * 128 + 2 * lane];
            union { unsigned int i; float f; } lo, hi;
            lo.i = u << 16; hi.i = u & 0xffff0000u;
            acc0 = fmaf(wA, lo.f, acc0);
            acc1 = fmaf(wA, hi.f, acc1);
        }
    }

    if (!nact) return;
    const int o2 = n * 128 + 2 * lane;
    if (MODE == 2) {
        float* outf = (float*)out;
        float2 cur = *(float2*)&outf[o2];
        cur.x += acc0; cur.y += acc1;
        *(float2*)&outf[o2] = cur;
    } else if (MODE == 3) {
        const float b0 = ldx(bias, 2 * lane, bf), b1 = ldx(bias, 2 * lane + 1, bf);
        const float r0 = ((const float*)resid)[o2], r1 = ((const float*)resid)[o2 + 1];
        const float v0 = (accIn[o2]     + acc0) * 0.25f + b0 + r0;
        const float v1 = (accIn[o2 + 1] + acc1) * 0.25f + b1 + r1;
        if (bf) {
            ((unsigned short*)out)[o2]     = f2us(v0);
            ((unsigned short*)out)[o2 + 1] = f2us(v1);
        } else {
            ((float*)out)[o2]     = v0;
            ((float*)out)[o2 + 1] = v1;
        }
    } else {
        float* outf = (float*)out;
        const float b0 = ldx(bias, 2 * lane, bf), b1 = ldx(bias, 2 * lane + 1, bf);
        float r0, r1;
        if (MODE == 0) { r0 = ldx(resid, o2, bf); r1 = ldx(resid, o2 + 1, bf); }
        else           { r0 = ((const float*)resid)[o2]; r1 = ((const float*)resid)[o2 + 1]; }
        const float v0 = acc0 + b0 + r0;
        const float v1 = acc1 + b1 + r1;
        float2 o;
        o.x = v0 > 0.f ? v0 : expm1f(v0);
        o.y = v1 > 0.f ? v1 : expm1f(v1);
        *(float2*)&outf[o2] = o;
    }
}

extern "C" void kernel_launch(void* const* d_in, const int* in_sizes, int n_in,
                              void* d_out, int out_size, void* d_ws, size_t ws_size,
                              hipStream_t stream) {
    const int N  = in_sizes[0] / 128;
    const int E  = in_sizes[1] / 2;
    const int EP = E + N;

    const void* x   = d_in[0];
    const void* ei  = d_in[1];
    const void* W1  = d_in[2];
    const void* as1 = d_in[3];
    const void* ad1 = d_in[4];
    const void* b1  = d_in[5];
    const void* W2  = d_in[6];
    const void* as2 = d_in[7];
    const void* ad2 = d_in[8];
    const void* b2  = d_in[9];
    const void* W3  = d_in[10];
    const void* as3 = d_in[11];
    const void* ad3 = d_in[12];
    const void* b3  = d_in[13];

    char* p = (char*)d_ws;
    auto alloc = [&](size_t bytes) { char* r = p; p += (bytes + 255) & ~(size_t)255; return r; };
    int*   flags = (int*)alloc(8);
    int*   deg   = (int*)alloc((size_t)(N + 1) * 4);
    int*   coff  = (int*)alloc((size_t)(N + 1) * 4);
    int*   cpos  = (int*)alloc((size_t)N * 4);
    int*   part  = (int*)alloc(4096);
    int*   csrc  = (int*)alloc((size_t)EP * 4);
    float* hbuf  = (float*)alloc((size_t)N * 128 * 4);
    float* x1b   = (float*)alloc((size_t)N * 128 * 4);
    float* x2b   = (float*)alloc((size_t)N * 128 * 4);
    float* accb  = (float*)alloc((size_t)N * 128 * 4);
    float* ssrc  = (float*)alloc((size_t)N * 4 * 4);
    float* sdst  = (float*)alloc((size_t)N * 4 * 4);

    // bf16 h shadows alias dead buffers (keeps ws footprint unchanged):
    unsigned short* h16_12 = (unsigned short*)accb;  // layers 1-2 (accb re-zeroed later)
    unsigned short* h16_3  = (unsigned short*)x1b;   // layer 3 (x1 dead after layer 2)

    hipMemsetAsync(deg,  0, (size_t)(N + 1) * 4, stream);
    hipMemsetAsync(cpos, 0, (size_t)N * 4, stream);

    k_detect<<<1, 64, 0, stream>>>((const unsigned short*)x, (const unsigned int*)ei, flags);

    const int egrid = (EP + 255) / 256;
    const int nblk  = (N + 1023) / 1024;
    k_hist<<<egrid, 256, 0, stream>>>(ei, flags, deg, E, N);
    k_scan_a<<<nblk, 1024, 0, stream>>>(deg, coff, part, N);
    k_scan_b<<<1, 1024, 0, stream>>>(part, coff, nblk, N);
    k_scan_c<<<nblk, 1024, 0, stream>>>(coff, part, N);
    k_scatter<<<egrid, 256, 0, stream>>>(ei, flags, coff, cpos, csrc, E, N);

    const int ggrid = (N + 63) / 64;
    const int ngrid = (N + 3) / 4;

    // ---- layer 1
    k_gemm<true ><<<ggrid, 256, 0, stream>>>(x,   W1, hbuf, h16_12, flags, N, 128, 0);
    k_scores<32><<<ngrid, 256, 0, stream>>>(hbuf, as1, ad1, 0, flags, ssrc, sdst, N);
    k_agg<4, 0><<<ngrid, 256, 0, stream>>>(coff, csrc, ssrc, sdst, h16_12, b1, x,
                                           nullptr, flags, x1b, N);

    // ---- layer 2
    k_gemm<false><<<ggrid, 256, 0, stream>>>(x1b, W2, hbuf, h16_12, flags, N, 128, 0);
    k_scores<32><<<ngrid, 256, 0, stream>>>(hbuf, as2, ad2, 0, flags, ssrc, sdst, N);
    k_agg<4, 1><<<ngrid, 256, 0, stream>>>(coff, csrc, ssrc, sdst, h16_12, b2, x1b,
                                           nullptr, flags, x2b, N);

    // ---- layer 3: mean over 4 heads; head 3 fuses the final epilogue
    hipMemsetAsync(accb, 0, (size_t)N * 128 * 4, stream);
    for (int h = 0; h < 3; ++h) {
        k_gemm<false><<<ggrid, 256, 0, stream>>>(x2b, W3, hbuf, h16_3, flags, N, 512, h * 128);
        k_scores<128><<<ngrid, 256, 0, stream>>>(hbuf, as3, ad3, h * 128, flags, ssrc, sdst, N);
        k_agg<1, 2><<<ngrid, 256, 0, stream>>>(coff, csrc, ssrc, sdst, h16_3, nullptr, nullptr,
                                               nullptr, flags, accb, N);
    }
    k_gemm<false><<<ggrid, 256, 0, stream>>>(x2b, W3, hbuf, h16_3, flags, N, 512, 3 * 128);
    k_scores<128><<<ngrid, 256, 0, stream>>>(hbuf, as3, ad3, 3 * 128, flags, ssrc, sdst, N);
    k_agg<1, 3><<<ngrid, 256, 0, stream>>>(coff, csrc, ssrc, sdst, h16_3, b3, x2b,
                                           accb, flags, d_out, N);
}

// Round 6
// 841.075 us; speedup vs baseline: 2.6605x; 1.4357x over previous
//
#include <hip/hip_runtime.h>
#include <hip/hip_bf16.h>
#include <cstdint>

#define NEG_SLOPE 0.2f

typedef __bf16 bf16x8 __attribute__((ext_vector_type(8)));
typedef float  floatx4 __attribute__((ext_vector_type(4)));

// ---------- bf16 helpers ----------
__device__ __forceinline__ float us2f(unsigned short u) {
    union { unsigned int i; float f; } c; c.i = ((unsigned int)u) << 16; return c.f;
}
__device__ __forceinline__ unsigned short f2us(float f) {
    union { float f; unsigned int i; } c; c.f = f;
    unsigned int x = c.i;
    unsigned int r = (x + 0x7fffu + ((x >> 16) & 1u)) >> 16;   // RNE
    return (unsigned short)r;
}
__device__ __forceinline__ float ldx(const void* p, int i, int bf) {
    return bf ? us2f(((const unsigned short*)p)[i]) : ((const float*)p)[i];
}
__device__ __forceinline__ void split2(float f, unsigned short& h, unsigned short& l) {
    h = f2us(f);
    l = f2us(f - us2f(h));
}

// ---------- runtime dtype probes ----------
__global__ void k_detect(const unsigned short* __restrict__ x16,
                         const unsigned int* __restrict__ ei,
                         int* __restrict__ flags) {
    if (threadIdx.x == 0 && blockIdx.x == 0) {
        int cnt = 0;
        for (int i = 0; i < 1024; ++i) {
            const unsigned short u = x16[2 * i];
            const int e = (u >> 7) & 0xFF;
            if (e < 100 || e > 160) ++cnt;
        }
        flags[0] = (cnt < 256) ? 1 : 0;      // bf16?
        int is64 = 1;
        for (int i = 0; i < 64; ++i)
            if (ei[2 * i + 1] != 0u) { is64 = 0; break; }
        flags[1] = is64;                      // int64?
    }
}

__device__ __forceinline__ int edge_at(const void* ei, int f64, long long idx) {
    if (f64) return (int)((const long long*)ei)[idx];
    return ((const int*)ei)[idx];
}

// ---------- CSR build ----------
__global__ void k_hist(const void* __restrict__ ei, const int* __restrict__ flags,
                       int* __restrict__ deg, int E, int N) {
    const int f64 = flags[1];
    const int EP = E + N;
    for (int e = blockIdx.x * blockDim.x + threadIdx.x; e < EP; e += gridDim.x * blockDim.x) {
        int dst = (e < E) ? edge_at(ei, f64, (long long)E + e) : (e - E);
        atomicAdd(&deg[dst], 1);
    }
}

__global__ __launch_bounds__(1024) void k_scan_a(const int* __restrict__ deg,
                                                 int* __restrict__ coff,
                                                 int* __restrict__ part, int N) {
    __shared__ int tmp[1024];
    const int t = threadIdx.x, idx = blockIdx.x * 1024 + t;
    const int v = (idx < N) ? deg[idx] : 0;
    tmp[t] = v; __syncthreads();
    for (int s = 1; s < 1024; s <<= 1) {
        int a = (t >= s) ? tmp[t - s] : 0;
        __syncthreads(); tmp[t] += a; __syncthreads();
    }
    if (idx < N) coff[idx] = tmp[t] - v;
    if (t == 1023) part[blockIdx.x] = tmp[1023];
}

__global__ __launch_bounds__(1024) void k_scan_b(int* __restrict__ part,
                                                 int* __restrict__ coff, int nblk, int N) {
    __shared__ int tmp[1024];
    const int t = threadIdx.x;
    const int v = (t < nblk) ? part[t] : 0;
    tmp[t] = v; __syncthreads();
    for (int s = 1; s < 1024; s <<= 1) {
        int a = (t >= s) ? tmp[t - s] : 0;
        __syncthreads(); tmp[t] += a; __syncthreads();
    }
    if (t < nblk) part[t] = tmp[t] - v;
    if (t == 1023) coff[N] = tmp[1023];
}

__global__ __launch_bounds__(1024) void k_scan_c(int* __restrict__ coff,
                                                 const int* __restrict__ part, int N) {
    const int idx = blockIdx.x * 1024 + threadIdx.x;
    if (idx < N) coff[idx] += part[blockIdx.x];
}

__global__ void k_scatter(const void* __restrict__ ei, const int* __restrict__ flags,
                          const int* __restrict__ coff, int* __restrict__ cpos,
                          int* __restrict__ csrc, int E, int N) {
    const int f64 = flags[1];
    const int EP = E + N;
    for (int e = blockIdx.x * blockDim.x + threadIdx.x; e < EP; e += gridDim.x * blockDim.x) {
        int src, dst;
        if (e < E) { src = edge_at(ei, f64, e); dst = edge_at(ei, f64, (long long)E + e); }
        else       { src = dst = e - E; }
        const int p = atomicAdd(&cpos[dst], 1);
        csrc[coff[dst] + p] = src;
    }
}

// ---------- W -> MFMA B-fragment pre-shuffle (hi/lo planes) ----------
// out idx = ((blk*8 + ntg)*4 + ks)*512 + lane*8 + j
// value    = W[ks*32 + (lane>>4)*8 + j][blk*128 + ntg*16 + (lane&15)]
__global__ void k_wfrag(const void* __restrict__ Wv, const int* __restrict__ flags,
                        int wstride, int total,
                        unsigned short* __restrict__ outH, unsigned short* __restrict__ outL) {
    const int bf = flags[0];
    for (int tid = blockIdx.x * blockDim.x + threadIdx.x; tid < total;
         tid += gridDim.x * blockDim.x) {
        const int j    = tid & 7;
        const int lane = (tid >> 3) & 63;
        const int ks   = (tid >> 9) & 3;
        const int ntg  = (tid >> 11) & 7;
        const int blk  = tid >> 14;
        const int k = ks * 32 + (lane >> 4) * 8 + j;
        const int c = blk * 128 + ntg * 16 + (lane & 15);
        const float v = ldx(Wv, k * wstride + c, bf);
        unsigned short h, l; split2(v, h, l);
        outH[tid] = h; outL[tid] = l;
    }
}

// ---------- MFMA GEMM with fused scores epilogue ----------
// h16[n,0:128) bf16 = X[n,0:128] @ W-block; scores reduced in-register.
// SC=0: 4 heads of 32 (wave wv == head wv), ssrc/sdst [N*4]
// SC=1: single head of 128 (cross-wave LDS reduce), ssrc/sdst [N]
template <bool XRAW, int SC>
__global__ __launch_bounds__(256) void k_gemm(const void* __restrict__ Xv,
                                              const unsigned short* __restrict__ whf,
                                              const unsigned short* __restrict__ wlf,
                                              unsigned short* __restrict__ Y16,
                                              float* __restrict__ ssrc,
                                              float* __restrict__ sdst,
                                              const void* __restrict__ a_src,
                                              const void* __restrict__ a_dst,
                                              int aoff,
                                              const int* __restrict__ flags,
                                              int N) {
    __shared__ __align__(16) unsigned short Ah[64][136], Al[64][136];
    __shared__ float sred[2][4][SC ? 64 : 1];
    const int bf   = flags[0];
    const int t    = threadIdx.x;
    const int row0 = blockIdx.x * 64;
    const int wv   = t >> 6;
    const int lane = t & 63;
    const int quad = lane >> 4;
    const int l16  = lane & 15;

    // stage A: 64 rows x 128 k, hi/lo planes
#pragma unroll
    for (int it = 0; it < 8; ++it) {
        const int id = it * 256 + t;
        const int r  = id >> 5;
        const int c  = (id & 31) * 4;
        const int gr = row0 + r;
        ushort4 h4 = make_ushort4(0, 0, 0, 0), l4 = make_ushort4(0, 0, 0, 0);
        if (gr < N) {
            if (XRAW && bf) {
                h4 = *(const ushort4*)&((const unsigned short*)Xv)[(size_t)gr * 128 + c];
            } else {
                const float4 f = *(const float4*)&((const float*)Xv)[(size_t)gr * 128 + c];
                split2(f.x, h4.x, l4.x); split2(f.y, h4.y, l4.y);
                split2(f.z, h4.z, l4.z); split2(f.w, h4.w, l4.w);
            }
        }
        *(ushort4*)&Ah[r][c] = h4;
        *(ushort4*)&Al[r][c] = l4;
    }
    __syncthreads();

    floatx4 acc[4][2];
#pragma unroll
    for (int mt = 0; mt < 4; ++mt)
#pragma unroll
        for (int nt = 0; nt < 2; ++nt) acc[mt][nt] = (floatx4){0.f, 0.f, 0.f, 0.f};

#pragma unroll
    for (int ks = 0; ks < 4; ++ks) {
        const int ko = ks * 32 + quad * 8;
        bf16x8 ah[4], al[4], bh[2], bl[2];
#pragma unroll
        for (int mt = 0; mt < 4; ++mt) ah[mt] = *(const bf16x8*)&Ah[mt * 16 + l16][ko];
        if (!(XRAW && bf)) {
#pragma unroll
            for (int mt = 0; mt < 4; ++mt) al[mt] = *(const bf16x8*)&Al[mt * 16 + l16][ko];
        }
#pragma unroll
        for (int nt = 0; nt < 2; ++nt)
            bh[nt] = *(const bf16x8*)&whf[(((wv * 2 + nt) * 4 + ks) * 64 + lane) * 8];
        if (!bf) {
#pragma unroll
            for (int nt = 0; nt < 2; ++nt)
                bl[nt] = *(const bf16x8*)&wlf[(((wv * 2 + nt) * 4 + ks) * 64 + lane) * 8];
        }
#pragma unroll
        for (int mt = 0; mt < 4; ++mt)
#pragma unroll
            for (int nt = 0; nt < 2; ++nt) {
                acc[mt][nt] = __builtin_amdgcn_mfma_f32_16x16x32_bf16(ah[mt], bh[nt], acc[mt][nt], 0, 0, 0);
                if (!bf)
                    acc[mt][nt] = __builtin_amdgcn_mfma_f32_16x16x32_bf16(ah[mt], bl[nt], acc[mt][nt], 0, 0, 0);
                if (!(XRAW && bf))
                    acc[mt][nt] = __builtin_amdgcn_mfma_f32_16x16x32_bf16(al[mt], bh[nt], acc[mt][nt], 0, 0, 0);
            }
    }

    // a-vector values for this wave's 32 columns
    const int aBase = aoff + wv * 32;
    float as_[2], ad_[2];
#pragma unroll
    for (int nt = 0; nt < 2; ++nt) {
        as_[nt] = ldx(a_src, aBase + nt * 16 + l16, bf);
        ad_[nt] = ldx(a_dst, aBase + nt * 16 + l16, bf);
    }

    // store bf16 h + fused score reduction
#pragma unroll
    for (int mt = 0; mt < 4; ++mt) {
        const int rl = mt * 16 + quad * 4;   // local row base
#pragma unroll
        for (int r = 0; r < 4; ++r) {
            const int grow = row0 + rl + r;
            if (grow < N) {
#pragma unroll
                for (int nt = 0; nt < 2; ++nt)
                    Y16[(size_t)grow * 128 + wv * 32 + nt * 16 + l16] = f2us(acc[mt][nt][r]);
            }
            float ps = acc[mt][0][r] * as_[0] + acc[mt][1][r] * as_[1];
            float pd = acc[mt][0][r] * ad_[0] + acc[mt][1][r] * ad_[1];
#pragma unroll
            for (int mk = 1; mk <= 8; mk <<= 1) {
                ps += __shfl_xor(ps, mk);
                pd += __shfl_xor(pd, mk);
            }
            if (SC == 0) {
                if (l16 == 0 && grow < N) {
                    ssrc[(size_t)grow * 4 + wv] = ps;
                    sdst[(size_t)grow * 4 + wv] = pd;
                }
            } else {
                if (l16 == 0) { sred[0][wv][rl + r] = ps; sred[1][wv][rl + r] = pd; }
            }
        }
    }
    if (SC == 1) {
        __syncthreads();
        if (t < 64 && row0 + t < N) {
            ssrc[row0 + t] = sred[0][0][t] + sred[0][1][t] + sred[0][2][t] + sred[0][3][t];
            sdst[row0 + t] = sred[1][0][t] + sred[1][1][t] + sred[1][2][t] + sred[1][3][t];
        }
    }
}

// ---------- softmax + aggregation; one wave per node; bf16 gather ----------
// MODE 0: out = elu(acc + bias + raw resid)     out f32
// MODE 1: out = elu(acc + bias + f32 resid)     out f32
// MODE 2: out += acc                            out f32
// MODE 3: final = cast((accIn+acc)*0.25 + bias + f32 resid)  out = d_out
template <int NUMS, int MODE>
__global__ __launch_bounds__(256) void k_agg(const int* __restrict__ coff,
                                             const int* __restrict__ csrc,
                                             const float* __restrict__ ssrc,
                                             const float* __restrict__ sdst,
                                             const unsigned short* __restrict__ H16,
                                             const void* __restrict__ bias,
                                             const void* __restrict__ resid,
                                             const float* __restrict__ accIn,
                                             const int* __restrict__ flags,
                                             void* __restrict__ out, int N) {
    __shared__ int   sS[4][64];
    __shared__ float wS[4][64 * NUMS];
    const int bf   = flags[0];
    const int wv   = threadIdx.x >> 6;
    const int lane = threadIdx.x & 63;
    const int n0   = blockIdx.x * 4 + wv;
    const bool nact = n0 < N;
    const int n    = nact ? n0 : (N - 1);
    const int beg = coff[n], end = coff[n + 1];
    const int deg = end - beg;
    const int myh = (NUMS == 4) ? (lane >> 4) : 0;

    float sd[NUMS];
#pragma unroll
    for (int h = 0; h < NUMS; ++h) sd[h] = sdst[n * NUMS + h];

    const bool fast = (deg <= 64);
    float m[NUMS], z[NUMS];

    if (fast) {
        const bool act = lane < deg;
        int myS = 0;
        float v[NUMS];
#pragma unroll
        for (int h = 0; h < NUMS; ++h) v[h] = -1e30f;
        if (act) {
            myS = csrc[beg + lane];
            if (NUMS == 4) {
                const float4 sp = *(const float4*)&ssrc[(size_t)myS * 4];
                const float s4[4] = { sp.x, sp.y, sp.z, sp.w };
#pragma unroll
                for (int h = 0; h < 4; ++h) {
                    float tv = s4[h] + sd[h];
                    v[h] = tv >= 0.f ? tv : NEG_SLOPE * tv;
                }
            } else {
                float tv = ssrc[myS] + sd[0];
                v[0] = tv >= 0.f ? tv : NEG_SLOPE * tv;
            }
        }
#pragma unroll
        for (int h = 0; h < NUMS; ++h) m[h] = v[h];
#pragma unroll
        for (int mk = 1; mk <= 32; mk <<= 1)
#pragma unroll
            for (int h = 0; h < NUMS; ++h) m[h] = fmaxf(m[h], __shfl_xor(m[h], mk));
        float w[NUMS];
#pragma unroll
        for (int h = 0; h < NUMS; ++h) w[h] = act ? expf(v[h] - m[h]) : 0.f;
#pragma unroll
        for (int h = 0; h < NUMS; ++h) z[h] = w[h];
#pragma unroll
        for (int mk = 1; mk <= 32; mk <<= 1)
#pragma unroll
            for (int h = 0; h < NUMS; ++h) z[h] += __shfl_xor(z[h], mk);
        if (act) {
            sS[wv][lane] = myS;
#pragma unroll
            for (int h = 0; h < NUMS; ++h)
                wS[wv][lane * NUMS + h] = w[h] / (z[h] + 1e-16f);
        }
    } else {
#pragma unroll
        for (int h = 0; h < NUMS; ++h) m[h] = -1e30f;
        for (int e = beg + lane; e < end; e += 64) {
            const int s = csrc[e];
#pragma unroll
            for (int h = 0; h < NUMS; ++h) {
                float tv = ssrc[(size_t)s * NUMS + h] + sd[h];
                tv = tv >= 0.f ? tv : NEG_SLOPE * tv;
                m[h] = fmaxf(m[h], tv);
            }
        }
#pragma unroll
        for (int mk = 1; mk <= 32; mk <<= 1)
#pragma unroll
            for (int h = 0; h < NUMS; ++h) m[h] = fmaxf(m[h], __shfl_xor(m[h], mk));
#pragma unroll
        for (int h = 0; h < NUMS; ++h) z[h] = 0.f;
        for (int e = beg + lane; e < end; e += 64) {
            const int s = csrc[e];
#pragma unroll
            for (int h = 0; h < NUMS; ++h) {
                float tv = ssrc[(size_t)s * NUMS + h] + sd[h];
                tv = tv >= 0.f ? tv : NEG_SLOPE * tv;
                z[h] += expf(tv - m[h]);
            }
        }
#pragma unroll
        for (int mk = 1; mk <= 32; mk <<= 1)
#pragma unroll
            for (int h = 0; h < NUMS; ++h) z[h] += __shfl_xor(z[h], mk);
    }

    __syncthreads();

    float acc0 = 0.f, acc1 = 0.f;
    if (fast) {
        for (int e = 0; e < deg; ++e) {
            const int   s  = sS[wv][e];
            const float wA = wS[wv][e * NUMS + myh];
            const unsigned int u = *(const unsigned int*)&H16[(size_t)s * 128 + 2 * lane];
            union { unsigned int i; float f; } lo, hi;
            lo.i = u << 16; hi.i = u & 0xffff0000u;
            acc0 = fmaf(wA, lo.f, acc0);
            acc1 = fmaf(wA, hi.f, acc1);
        }
    } else {
        const float mh  = m[myh];
        const float ivh = 1.f / (z[myh] + 1e-16f);
        const float sdh = sd[myh];
        for (int e = beg; e < end; ++e) {
            const int s = csrc[e];
            float tv = ssrc[(size_t)s * NUMS + myh] + sdh;
            tv = tv >= 0.f ? tv : NEG_SLOPE * tv;
            const float wA = expf(tv - mh) * ivh;
            const unsigned int u = *(const unsigned int*)&H16[(size_t)s * 128 + 2 * lane];
            union { unsigned int i; float f; } lo, hi;
            lo.i = u << 16; hi.i = u & 0xffff0000u;
            acc0 = fmaf(wA, lo.f, acc0);
            acc1 = fmaf(wA, hi.f, acc1);
        }
    }

    if (!nact) return;
    const int o2 = n * 128 + 2 * lane;
    if (MODE == 2) {
        float* outf = (float*)out;
        float2 cur = *(float2*)&outf[o2];
        cur.x += acc0; cur.y += acc1;
        *(float2*)&outf[o2] = cur;
    } else if (MODE == 3) {
        const float b0 = ldx(bias, 2 * lane, bf), b1 = ldx(bias, 2 * lane + 1, bf);
        const float r0 = ((const float*)resid)[o2], r1 = ((const float*)resid)[o2 + 1];
        const float v0 = (accIn[o2]     + acc0) * 0.25f + b0 + r0;
        const float v1 = (accIn[o2 + 1] + acc1) * 0.25f + b1 + r1;
        if (bf) {
            ((unsigned short*)out)[o2]     = f2us(v0);
            ((unsigned short*)out)[o2 + 1] = f2us(v1);
        } else {
            ((float*)out)[o2]     = v0;
            ((float*)out)[o2 + 1] = v1;
        }
    } else {
        float* outf = (float*)out;
        const float b0 = ldx(bias, 2 * lane, bf), b1 = ldx(bias, 2 * lane + 1, bf);
        float r0, r1;
        if (MODE == 0) { r0 = ldx(resid, o2, bf); r1 = ldx(resid, o2 + 1, bf); }
        else           { r0 = ((const float*)resid)[o2]; r1 = ((const float*)resid)[o2 + 1]; }
        const float v0 = acc0 + b0 + r0;
        const float v1 = acc1 + b1 + r1;
        float2 o;
        o.x = v0 > 0.f ? v0 : expm1f(v0);
        o.y = v1 > 0.f ? v1 : expm1f(v1);
        *(float2*)&outf[o2] = o;
    }
}

extern "C" void kernel_launch(void* const* d_in, const int* in_sizes, int n_in,
                              void* d_out, int out_size, void* d_ws, size_t ws_size,
                              hipStream_t stream) {
    const int N  = in_sizes[0] / 128;
    const int E  = in_sizes[1] / 2;
    const int EP = E + N;

    const void* x   = d_in[0];
    const void* ei  = d_in[1];
    const void* W1  = d_in[2];
    const void* as1 = d_in[3];
    const void* ad1 = d_in[4];
    const void* b1  = d_in[5];
    const void* W2  = d_in[6];
    const void* as2 = d_in[7];
    const void* ad2 = d_in[8];
    const void* b2  = d_in[9];
    const void* W3  = d_in[10];
    const void* as3 = d_in[11];
    const void* ad3 = d_in[12];
    const void* b3  = d_in[13];

    char* p = (char*)d_ws;
    auto alloc = [&](size_t bytes) { char* r = p; p += (bytes + 255) & ~(size_t)255; return r; };
    int*   flags = (int*)alloc(8);
    int*   deg   = (int*)alloc((size_t)(N + 1) * 4);
    int*   coff  = (int*)alloc((size_t)(N + 1) * 4);
    int*   cpos  = (int*)alloc((size_t)N * 4);
    int*   part  = (int*)alloc(4096);
    int*   csrc  = (int*)alloc((size_t)EP * 4);
    float* x1b   = (float*)alloc((size_t)N * 128 * 4);
    float* x2b   = (float*)alloc((size_t)N * 128 * 4);
    float* accb  = (float*)alloc((size_t)N * 128 * 4);
    float* ssrc  = (float*)alloc((size_t)N * 4 * 4);
    float* sdst  = (float*)alloc((size_t)N * 4 * 4);
    unsigned short* whf1 = (unsigned short*)alloc(16384 * 2);
    unsigned short* wlf1 = (unsigned short*)alloc(16384 * 2);
    unsigned short* whf2 = (unsigned short*)alloc(16384 * 2);
    unsigned short* wlf2 = (unsigned short*)alloc(16384 * 2);
    unsigned short* whf3 = (unsigned short*)alloc(65536 * 2);
    unsigned short* wlf3 = (unsigned short*)alloc(65536 * 2);

    // bf16 h shadows alias dead f32 buffers
    unsigned short* h16_12 = (unsigned short*)accb;  // layers 1-2 (accb re-zeroed later)
    unsigned short* h16_3  = (unsigned short*)x1b;   // layer 3 (x1 dead after layer 2)

    hipMemsetAsync(deg,  0, (size_t)(N + 1) * 4, stream);
    hipMemsetAsync(cpos, 0, (size_t)N * 4, stream);

    k_detect<<<1, 64, 0, stream>>>((const unsigned short*)x, (const unsigned int*)ei, flags);

    // pre-shuffle weights into MFMA B-fragment order
    k_wfrag<<<64, 256, 0, stream>>>(W1, flags, 128, 16384, whf1, wlf1);
    k_wfrag<<<64, 256, 0, stream>>>(W2, flags, 128, 16384, whf2, wlf2);
    k_wfrag<<<256, 256, 0, stream>>>(W3, flags, 512, 65536, whf3, wlf3);

    const int egrid = (EP + 255) / 256;
    const int nblk  = (N + 1023) / 1024;
    k_hist<<<egrid, 256, 0, stream>>>(ei, flags, deg, E, N);
    k_scan_a<<<nblk, 1024, 0, stream>>>(deg, coff, part, N);
    k_scan_b<<<1, 1024, 0, stream>>>(part, coff, nblk, N);
    k_scan_c<<<nblk, 1024, 0, stream>>>(coff, part, N);
    k_scatter<<<egrid, 256, 0, stream>>>(ei, flags, coff, cpos, csrc, E, N);

    const int ggrid = (N + 63) / 64;
    const int ngrid = (N + 3) / 4;

    // ---- layer 1
    k_gemm<true, 0><<<ggrid, 256, 0, stream>>>(x, whf1, wlf1, h16_12, ssrc, sdst,
                                               as1, ad1, 0, flags, N);
    k_agg<4, 0><<<ngrid, 256, 0, stream>>>(coff, csrc, ssrc, sdst, h16_12, b1, x,
                                           nullptr, flags, x1b, N);

    // ---- layer 2
    k_gemm<false, 0><<<ggrid, 256, 0, stream>>>(x1b, whf2, wlf2, h16_12, ssrc, sdst,
                                                as2, ad2, 0, flags, N);
    k_agg<4, 1><<<ngrid, 256, 0, stream>>>(coff, csrc, ssrc, sdst, h16_12, b2, x1b,
                                           nullptr, flags, x2b, N);

    // ---- layer 3: mean over 4 heads; head 3 fuses the final epilogue
    hipMemsetAsync(accb, 0, (size_t)N * 128 * 4, stream);
    for (int h = 0; h < 3; ++h) {
        k_gemm<false, 1><<<ggrid, 256, 0, stream>>>(x2b, whf3 + h * 16384, wlf3 + h * 16384,
                                                    h16_3, ssrc, sdst, as3, ad3, h * 128,
                                                    flags, N);
        k_agg<1, 2><<<ngrid, 256, 0, stream>>>(coff, csrc, ssrc, sdst, h16_3, nullptr, nullptr,
                                               nullptr, flags, accb, N);
    }
    k_gemm<false, 1><<<ggrid, 256, 0, stream>>>(x2b, whf3 + 3 * 16384, wlf3 + 3 * 16384,
                                                h16_3, ssrc, sdst, as3, ad3, 3 * 128,
                                                flags, N);
    k_agg<1, 3><<<ngrid, 256, 0, stream>>>(coff, csrc, ssrc, sdst, h16_3, b3, x2b,
                                           accb, flags, d_out, N);
}

// Round 7
// 788.789 us; speedup vs baseline: 2.8368x; 1.0663x over previous
//
#include <hip/hip_runtime.h>
#include <hip/hip_bf16.h>
#include <cstdint>

#define NEG_SLOPE 0.2f

typedef __bf16 bf16x8 __attribute__((ext_vector_type(8)));
typedef float  floatx4 __attribute__((ext_vector_type(4)));

// ---------- bf16 helpers ----------
__device__ __forceinline__ float us2f(unsigned short u) {
    union { unsigned int i; float f; } c; c.i = ((unsigned int)u) << 16; return c.f;
}
__device__ __forceinline__ unsigned short f2us(float f) {
    union { float f; unsigned int i; } c; c.f = f;
    unsigned int x = c.i;
    unsigned int r = (x + 0x7fffu + ((x >> 16) & 1u)) >> 16;   // RNE
    return (unsigned short)r;
}
__device__ __forceinline__ float ldx(const void* p, int i, int bf) {
    return bf ? us2f(((const unsigned short*)p)[i]) : ((const float*)p)[i];
}
__device__ __forceinline__ void split2(float f, unsigned short& h, unsigned short& l) {
    h = f2us(f);
    l = f2us(f - us2f(h));
}
__device__ __forceinline__ float sel4(const float* a, int i) {
    float lo = (i & 1) ? a[1] : a[0];
    float hi = (i & 1) ? a[3] : a[2];
    return (i & 2) ? hi : lo;
}
__device__ __forceinline__ void fma4(float w, uint2 u,
                                     float& a0, float& a1, float& a2, float& a3) {
    union { unsigned int i; float f; } t0, t1, t2, t3;
    t0.i = u.x << 16; t1.i = u.x & 0xffff0000u;
    t2.i = u.y << 16; t3.i = u.y & 0xffff0000u;
    a0 = fmaf(w, t0.f, a0); a1 = fmaf(w, t1.f, a1);
    a2 = fmaf(w, t2.f, a2); a3 = fmaf(w, t3.f, a3);
}

// ---------- runtime dtype probes ----------
__global__ void k_detect(const unsigned short* __restrict__ x16,
                         const unsigned int* __restrict__ ei,
                         int* __restrict__ flags) {
    if (threadIdx.x == 0 && blockIdx.x == 0) {
        int cnt = 0;
        for (int i = 0; i < 1024; ++i) {
            const unsigned short u = x16[2 * i];
            const int e = (u >> 7) & 0xFF;
            if (e < 100 || e > 160) ++cnt;
        }
        flags[0] = (cnt < 256) ? 1 : 0;      // bf16?
        int is64 = 1;
        for (int i = 0; i < 64; ++i)
            if (ei[2 * i + 1] != 0u) { is64 = 0; break; }
        flags[1] = is64;                      // int64?
    }
}

__device__ __forceinline__ int edge_at(const void* ei, int f64, long long idx) {
    if (f64) return (int)((const long long*)ei)[idx];
    return ((const int*)ei)[idx];
}

// ---------- CSR build ----------
__global__ void k_hist(const void* __restrict__ ei, const int* __restrict__ flags,
                       int* __restrict__ deg, int E, int N) {
    const int f64 = flags[1];
    const int EP = E + N;
    for (int e = blockIdx.x * blockDim.x + threadIdx.x; e < EP; e += gridDim.x * blockDim.x) {
        int dst = (e < E) ? edge_at(ei, f64, (long long)E + e) : (e - E);
        atomicAdd(&deg[dst], 1);
    }
}

__global__ __launch_bounds__(1024) void k_scan_a(const int* __restrict__ deg,
                                                 int* __restrict__ coff,
                                                 int* __restrict__ part, int N) {
    __shared__ int tmp[1024];
    const int t = threadIdx.x, idx = blockIdx.x * 1024 + t;
    const int v = (idx < N) ? deg[idx] : 0;
    tmp[t] = v; __syncthreads();
    for (int s = 1; s < 1024; s <<= 1) {
        int a = (t >= s) ? tmp[t - s] : 0;
        __syncthreads(); tmp[t] += a; __syncthreads();
    }
    if (idx < N) coff[idx] = tmp[t] - v;
    if (t == 1023) part[blockIdx.x] = tmp[1023];
}

__global__ __launch_bounds__(1024) void k_scan_b(int* __restrict__ part,
                                                 int* __restrict__ coff, int nblk, int N) {
    __shared__ int tmp[1024];
    const int t = threadIdx.x;
    const int v = (t < nblk) ? part[t] : 0;
    tmp[t] = v; __syncthreads();
    for (int s = 1; s < 1024; s <<= 1) {
        int a = (t >= s) ? tmp[t - s] : 0;
        __syncthreads(); tmp[t] += a; __syncthreads();
    }
    if (t < nblk) part[t] = tmp[t] - v;
    if (t == 1023) coff[N] = tmp[1023];
}

__global__ __launch_bounds__(1024) void k_scan_c(int* __restrict__ coff,
                                                 const int* __restrict__ part, int N) {
    const int idx = blockIdx.x * 1024 + threadIdx.x;
    if (idx < N) coff[idx] += part[blockIdx.x];
}

__global__ void k_scatter(const void* __restrict__ ei, const int* __restrict__ flags,
                          const int* __restrict__ coff, int* __restrict__ cpos,
                          int* __restrict__ csrc, int E, int N) {
    const int f64 = flags[1];
    const int EP = E + N;
    for (int e = blockIdx.x * blockDim.x + threadIdx.x; e < EP; e += gridDim.x * blockDim.x) {
        int src, dst;
        if (e < E) { src = edge_at(ei, f64, e); dst = edge_at(ei, f64, (long long)E + e); }
        else       { src = dst = e - E; }
        const int p = atomicAdd(&cpos[dst], 1);
        csrc[coff[dst] + p] = src;
    }
}

// ---------- W -> MFMA B-fragment pre-shuffle (hi/lo planes) ----------
__global__ void k_wfrag(const void* __restrict__ Wv, const int* __restrict__ flags,
                        int wstride, int total,
                        unsigned short* __restrict__ outH, unsigned short* __restrict__ outL) {
    const int bf = flags[0];
    for (int tid = blockIdx.x * blockDim.x + threadIdx.x; tid < total;
         tid += gridDim.x * blockDim.x) {
        const int j    = tid & 7;
        const int lane = (tid >> 3) & 63;
        const int ks   = (tid >> 9) & 3;
        const int ntg  = (tid >> 11) & 7;
        const int blk  = tid >> 14;
        const int k = ks * 32 + (lane >> 4) * 8 + j;
        const int c = blk * 128 + ntg * 16 + (lane & 15);
        const float v = ldx(Wv, k * wstride + c, bf);
        unsigned short h, l; split2(v, h, l);
        outH[tid] = h; outL[tid] = l;
    }
}

// ---------- MFMA GEMM with fused scores epilogue ----------
// blockIdx.y = head block (0 for layers 1/2; 0..3 for layer 3).
// SC=0: 4 heads of 32 (wave wv == head), ssrc/sdst [N*4]
// SC=1: one 128-col head per blockIdx.y, scores -> ssrc[n*4 + blockIdx.y]
template <bool XRAW, int SC>
__global__ __launch_bounds__(256) void k_gemm(const void* __restrict__ Xv,
                                              const unsigned short* __restrict__ whfB,
                                              const unsigned short* __restrict__ wlfB,
                                              unsigned short* __restrict__ Y16, int ystride,
                                              float* __restrict__ ssrc,
                                              float* __restrict__ sdst,
                                              const void* __restrict__ a_src,
                                              const void* __restrict__ a_dst,
                                              const int* __restrict__ flags,
                                              int N) {
    __shared__ __align__(16) unsigned short Ah[64][136], Al[64][136];
    __shared__ float sred[2][4][SC ? 64 : 1];
    const int bf   = flags[0];
    const int t    = threadIdx.x;
    const int row0 = blockIdx.x * 64;
    const int hy   = blockIdx.y;
    const unsigned short* whf = whfB + hy * 16384;
    const unsigned short* wlf = wlfB + hy * 16384;
    const int ycol0 = hy * 128;
    const int wv   = t >> 6;
    const int lane = t & 63;
    const int quad = lane >> 4;
    const int l16  = lane & 15;

#pragma unroll
    for (int it = 0; it < 8; ++it) {
        const int id = it * 256 + t;
        const int r  = id >> 5;
        const int c  = (id & 31) * 4;
        const int gr = row0 + r;
        ushort4 h4 = make_ushort4(0, 0, 0, 0), l4 = make_ushort4(0, 0, 0, 0);
        if (gr < N) {
            if (XRAW && bf) {
                h4 = *(const ushort4*)&((const unsigned short*)Xv)[(size_t)gr * 128 + c];
            } else {
                const float4 f = *(const float4*)&((const float*)Xv)[(size_t)gr * 128 + c];
                split2(f.x, h4.x, l4.x); split2(f.y, h4.y, l4.y);
                split2(f.z, h4.z, l4.z); split2(f.w, h4.w, l4.w);
            }
        }
        *(ushort4*)&Ah[r][c] = h4;
        *(ushort4*)&Al[r][c] = l4;
    }
    __syncthreads();

    floatx4 acc[4][2];
#pragma unroll
    for (int mt = 0; mt < 4; ++mt)
#pragma unroll
        for (int nt = 0; nt < 2; ++nt) acc[mt][nt] = (floatx4){0.f, 0.f, 0.f, 0.f};

#pragma unroll
    for (int ks = 0; ks < 4; ++ks) {
        const int ko = ks * 32 + quad * 8;
        bf16x8 ah[4], al[4], bh[2], bl[2];
#pragma unroll
        for (int mt = 0; mt < 4; ++mt) ah[mt] = *(const bf16x8*)&Ah[mt * 16 + l16][ko];
        if (!(XRAW && bf)) {
#pragma unroll
            for (int mt = 0; mt < 4; ++mt) al[mt] = *(const bf16x8*)&Al[mt * 16 + l16][ko];
        }
#pragma unroll
        for (int nt = 0; nt < 2; ++nt)
            bh[nt] = *(const bf16x8*)&whf[(((wv * 2 + nt) * 4 + ks) * 64 + lane) * 8];
        if (!bf) {
#pragma unroll
            for (int nt = 0; nt < 2; ++nt)
                bl[nt] = *(const bf16x8*)&wlf[(((wv * 2 + nt) * 4 + ks) * 64 + lane) * 8];
        }
#pragma unroll
        for (int mt = 0; mt < 4; ++mt)
#pragma unroll
            for (int nt = 0; nt < 2; ++nt) {
                acc[mt][nt] = __builtin_amdgcn_mfma_f32_16x16x32_bf16(ah[mt], bh[nt], acc[mt][nt], 0, 0, 0);
                if (!bf)
                    acc[mt][nt] = __builtin_amdgcn_mfma_f32_16x16x32_bf16(ah[mt], bl[nt], acc[mt][nt], 0, 0, 0);
                if (!(XRAW && bf))
                    acc[mt][nt] = __builtin_amdgcn_mfma_f32_16x16x32_bf16(al[mt], bh[nt], acc[mt][nt], 0, 0, 0);
            }
    }

    const int aBase = hy * 128 + wv * 32;
    float as_[2], ad_[2];
#pragma unroll
    for (int nt = 0; nt < 2; ++nt) {
        as_[nt] = ldx(a_src, aBase + nt * 16 + l16, bf);
        ad_[nt] = ldx(a_dst, aBase + nt * 16 + l16, bf);
    }

#pragma unroll
    for (int mt = 0; mt < 4; ++mt) {
        const int rl = mt * 16 + quad * 4;
#pragma unroll
        for (int r = 0; r < 4; ++r) {
            const int grow = row0 + rl + r;
            if (grow < N) {
#pragma unroll
                for (int nt = 0; nt < 2; ++nt)
                    Y16[(size_t)grow * ystride + ycol0 + wv * 32 + nt * 16 + l16] =
                        f2us(acc[mt][nt][r]);
            }
            float ps = acc[mt][0][r] * as_[0] + acc[mt][1][r] * as_[1];
            float pd = acc[mt][0][r] * ad_[0] + acc[mt][1][r] * ad_[1];
#pragma unroll
            for (int mk = 1; mk <= 8; mk <<= 1) {
                ps += __shfl_xor(ps, mk);
                pd += __shfl_xor(pd, mk);
            }
            if (SC == 0) {
                if (l16 == 0 && grow < N) {
                    ssrc[(size_t)grow * 4 + wv] = ps;
                    sdst[(size_t)grow * 4 + wv] = pd;
                }
            } else {
                if (l16 == 0) { sred[0][wv][rl + r] = ps; sred[1][wv][rl + r] = pd; }
            }
        }
    }
    if (SC == 1) {
        __syncthreads();
        if (t < 64 && row0 + t < N) {
            ssrc[(size_t)(row0 + t) * 4 + hy] = sred[0][0][t] + sred[0][1][t] + sred[0][2][t] + sred[0][3][t];
            sdst[(size_t)(row0 + t) * 4 + hy] = sred[1][0][t] + sred[1][1][t] + sred[1][2][t] + sred[1][3][t];
        }
    }
}

// ---------- softmax + aggregation; one wave per node; split-wave bf16 gather ----------
// MODE 0: out = elu(acc + bias + raw resid)        (layer 1, H stride 128)
// MODE 1: out = elu(acc + bias + f32 resid)        (layer 2, H stride 128)
// MODE 3: d_out = cast(acc*0.25 + bias + f32 resid) (layer 3, H stride 512, 4-head gather)
template <int MODE>
__global__ __launch_bounds__(256) void k_agg(const int* __restrict__ coff,
                                             const int* __restrict__ csrc,
                                             const float* __restrict__ ssrc,
                                             const float* __restrict__ sdst,
                                             const unsigned short* __restrict__ H16,
                                             const void* __restrict__ bias,
                                             const void* __restrict__ resid,
                                             const int* __restrict__ flags,
                                             void* __restrict__ out, int N) {
    __shared__ int   sS[4][64];
    __shared__ float wS[4][256];
    const int bf   = flags[0];
    const int wv   = threadIdx.x >> 6;
    const int lane = threadIdx.x & 63;
    const int n0   = blockIdx.x * 4 + wv;
    const bool nact = n0 < N;
    const int n    = nact ? n0 : (N - 1);
    const int beg = coff[n], end = coff[n + 1];
    const int deg = end - beg;

    const float4 sdv = *(const float4*)&sdst[(size_t)n * 4];
    float sd[4] = { sdv.x, sdv.y, sdv.z, sdv.w };

    const bool fast = (deg <= 64);
    float m[4], z[4];

    if (fast) {
        const bool act = lane < deg;
        int myS = 0;
        float v[4];
#pragma unroll
        for (int h = 0; h < 4; ++h) v[h] = -1e30f;
        if (act) {
            myS = csrc[beg + lane];
            const float4 sp = *(const float4*)&ssrc[(size_t)myS * 4];
            const float s4[4] = { sp.x, sp.y, sp.z, sp.w };
#pragma unroll
            for (int h = 0; h < 4; ++h) {
                float tv = s4[h] + sd[h];
                v[h] = tv >= 0.f ? tv : NEG_SLOPE * tv;
            }
        }
#pragma unroll
        for (int h = 0; h < 4; ++h) m[h] = v[h];
#pragma unroll
        for (int mk = 1; mk <= 32; mk <<= 1)
#pragma unroll
            for (int h = 0; h < 4; ++h) m[h] = fmaxf(m[h], __shfl_xor(m[h], mk));
        float w[4];
#pragma unroll
        for (int h = 0; h < 4; ++h) w[h] = act ? expf(v[h] - m[h]) : 0.f;
#pragma unroll
        for (int h = 0; h < 4; ++h) z[h] = w[h];
#pragma unroll
        for (int mk = 1; mk <= 32; mk <<= 1)
#pragma unroll
            for (int h = 0; h < 4; ++h) z[h] += __shfl_xor(z[h], mk);
        if (act) {
            sS[wv][lane] = myS;
#pragma unroll
            for (int h = 0; h < 4; ++h)
                wS[wv][lane * 4 + h] = w[h] / (z[h] + 1e-16f);
        }
    } else {
#pragma unroll
        for (int h = 0; h < 4; ++h) m[h] = -1e30f;
        for (int e = beg + lane; e < end; e += 64) {
            const int s = csrc[e];
            const float4 sp = *(const float4*)&ssrc[(size_t)s * 4];
            const float s4[4] = { sp.x, sp.y, sp.z, sp.w };
#pragma unroll
            for (int h = 0; h < 4; ++h) {
                float tv = s4[h] + sd[h];
                tv = tv >= 0.f ? tv : NEG_SLOPE * tv;
                m[h] = fmaxf(m[h], tv);
            }
        }
#pragma unroll
        for (int mk = 1; mk <= 32; mk <<= 1)
#pragma unroll
            for (int h = 0; h < 4; ++h) m[h] = fmaxf(m[h], __shfl_xor(m[h], mk));
#pragma unroll
        for (int h = 0; h < 4; ++h) z[h] = 0.f;
        for (int e = beg + lane; e < end; e += 64) {
            const int s = csrc[e];
            const float4 sp = *(const float4*)&ssrc[(size_t)s * 4];
            const float s4[4] = { sp.x, sp.y, sp.z, sp.w };
#pragma unroll
            for (int h = 0; h < 4; ++h) {
                float tv = s4[h] + sd[h];
                tv = tv >= 0.f ? tv : NEG_SLOPE * tv;
                z[h] += expf(tv - m[h]);
            }
        }
#pragma unroll
        for (int mk = 1; mk <= 32; mk <<= 1)
#pragma unroll
            for (int h = 0; h < 4; ++h) z[h] += __shfl_xor(z[h], mk);
    }

    __syncthreads();

    // split-wave gather: half-waves take alternating edges; lane covers 4 channels
    const int half = lane >> 5;
    const int l32  = lane & 31;
    const int c4   = l32 * 4;
    const int hd   = l32 >> 3;           // head owning channels c4..c4+3 (MODE<3)
    float a0 = 0.f, a1 = 0.f, a2 = 0.f, a3 = 0.f;

    if (fast) {
        for (int e0 = 0; e0 < deg; e0 += 2) {
            const int e = e0 + half;
            if (e < deg) {
                const int s = sS[wv][e];
                if (MODE < 3) {
                    const float w = wS[wv][e * 4 + hd];
                    const uint2 u = *(const uint2*)&H16[(size_t)s * 128 + c4];
                    fma4(w, u, a0, a1, a2, a3);
                } else {
                    const float4 w4 = *(const float4*)&wS[wv][e * 4];
                    const float wr[4] = { w4.x, w4.y, w4.z, w4.w };
#pragma unroll
                    for (int h = 0; h < 4; ++h) {
                        const uint2 u = *(const uint2*)&H16[(size_t)s * 512 + h * 128 + c4];
                        fma4(wr[h], u, a0, a1, a2, a3);
                    }
                }
            }
        }
    } else {
        float ivh[4];
#pragma unroll
        for (int h = 0; h < 4; ++h) ivh[h] = 1.f / (z[h] + 1e-16f);
        const float mh = sel4(m, hd), sdh = sel4(sd, hd), ih = sel4(ivh, hd);
        for (int e0 = 0; e0 < deg; e0 += 2) {
            const int e = e0 + half;
            if (e < deg) {
                const int s = csrc[beg + e];
                if (MODE < 3) {
                    float tv = ssrc[(size_t)s * 4 + hd] + sdh;
                    tv = tv >= 0.f ? tv : NEG_SLOPE * tv;
                    const float w = expf(tv - mh) * ih;
                    const uint2 u = *(const uint2*)&H16[(size_t)s * 128 + c4];
                    fma4(w, u, a0, a1, a2, a3);
                } else {
                    const float4 sp = *(const float4*)&ssrc[(size_t)s * 4];
                    const float s4[4] = { sp.x, sp.y, sp.z, sp.w };
#pragma unroll
                    for (int h = 0; h < 4; ++h) {
                        float tv = s4[h] + sd[h];
                        tv = tv >= 0.f ? tv : NEG_SLOPE * tv;
                        const float w = expf(tv - m[h]) * ivh[h];
                        const uint2 u = *(const uint2*)&H16[(size_t)s * 512 + h * 128 + c4];
                        fma4(w, u, a0, a1, a2, a3);
                    }
                }
            }
        }
    }

    // cross-half reduce: combine even/odd edge partial sums
    a0 += __shfl_xor(a0, 32);
    a1 += __shfl_xor(a1, 32);
    a2 += __shfl_xor(a2, 32);
    a3 += __shfl_xor(a3, 32);

    if (half != 0 || !nact) return;
    const int ob = n * 128 + c4;
    const float vv[4] = { a0, a1, a2, a3 };
    if (MODE == 3) {
        const float4 r4 = *(const float4*)&((const float*)resid)[ob];
        const float rr[4] = { r4.x, r4.y, r4.z, r4.w };
        if (bf) {
            ushort4 o;
            o.x = f2us(vv[0] * 0.25f + ldx(bias, c4 + 0, bf) + rr[0]);
            o.y = f2us(vv[1] * 0.25f + ldx(bias, c4 + 1, bf) + rr[1]);
            o.z = f2us(vv[2] * 0.25f + ldx(bias, c4 + 2, bf) + rr[2]);
            o.w = f2us(vv[3] * 0.25f + ldx(bias, c4 + 3, bf) + rr[3]);
            *(ushort4*)&((unsigned short*)out)[ob] = o;
        } else {
            float4 o;
            o.x = vv[0] * 0.25f + ldx(bias, c4 + 0, bf) + rr[0];
            o.y = vv[1] * 0.25f + ldx(bias, c4 + 1, bf) + rr[1];
            o.z = vv[2] * 0.25f + ldx(bias, c4 + 2, bf) + rr[2];
            o.w = vv[3] * 0.25f + ldx(bias, c4 + 3, bf) + rr[3];
            *(float4*)&((float*)out)[ob] = o;
        }
    } else {
        float rr[4];
        if (MODE == 0) {
#pragma unroll
            for (int i = 0; i < 4; ++i) rr[i] = ldx(resid, ob + i, bf);
        } else {
            const float4 r4 = *(const float4*)&((const float*)resid)[ob];
            rr[0] = r4.x; rr[1] = r4.y; rr[2] = r4.z; rr[3] = r4.w;
        }
        float o[4];
#pragma unroll
        for (int i = 0; i < 4; ++i) {
            const float v = vv[i] + ldx(bias, c4 + i, bf) + rr[i];
            o[i] = v > 0.f ? v : expm1f(v);
        }
        float4 o4 = make_float4(o[0], o[1], o[2], o[3]);
        *(float4*)&((float*)out)[ob] = o4;
    }
}

extern "C" void kernel_launch(void* const* d_in, const int* in_sizes, int n_in,
                              void* d_out, int out_size, void* d_ws, size_t ws_size,
                              hipStream_t stream) {
    const int N  = in_sizes[0] / 128;
    const int E  = in_sizes[1] / 2;
    const int EP = E + N;

    const void* x   = d_in[0];
    const void* ei  = d_in[1];
    const void* W1  = d_in[2];
    const void* as1 = d_in[3];
    const void* ad1 = d_in[4];
    const void* b1  = d_in[5];
    const void* W2  = d_in[6];
    const void* as2 = d_in[7];
    const void* ad2 = d_in[8];
    const void* b2  = d_in[9];
    const void* W3  = d_in[10];
    const void* as3 = d_in[11];
    const void* ad3 = d_in[12];
    const void* b3  = d_in[13];

    char* p = (char*)d_ws;
    auto alloc = [&](size_t bytes) { char* r = p; p += (bytes + 255) & ~(size_t)255; return r; };
    int*   flags = (int*)alloc(8);
    int*   deg   = (int*)alloc((size_t)(N + 1) * 4);
    int*   coff  = (int*)alloc((size_t)(N + 1) * 4);
    int*   cpos  = (int*)alloc((size_t)N * 4);
    int*   part  = (int*)alloc(4096);
    int*   csrc  = (int*)alloc((size_t)EP * 4);
    char*  region = alloc((size_t)N * 512 * 2);     // 102.4 MB union region
    float* x2b   = (float*)alloc((size_t)N * 128 * 4);
    float* ssrc  = (float*)alloc((size_t)N * 4 * 4);
    float* sdst  = (float*)alloc((size_t)N * 4 * 4);
    unsigned short* whf1 = (unsigned short*)alloc(16384 * 2);
    unsigned short* wlf1 = (unsigned short*)alloc(16384 * 2);
    unsigned short* whf2 = (unsigned short*)alloc(16384 * 2);
    unsigned short* wlf2 = (unsigned short*)alloc(16384 * 2);
    unsigned short* whf3 = (unsigned short*)alloc(65536 * 2);
    unsigned short* wlf3 = (unsigned short*)alloc(65536 * 2);

    // region layout: layers 1-2: [ x1b f32 51.2MB | h16_12 bf16 25.6MB | free ]
    //                layer 3:    [ h16all bf16 102.4MB ] (x1b, h16_12 dead by then)
    float*          x1b    = (float*)region;
    unsigned short* h16_12 = (unsigned short*)(region + (size_t)N * 128 * 4);
    unsigned short* h16all = (unsigned short*)region;

    hipMemsetAsync(deg,  0, (size_t)(N + 1) * 4, stream);
    hipMemsetAsync(cpos, 0, (size_t)N * 4, stream);

    k_detect<<<1, 64, 0, stream>>>((const unsigned short*)x, (const unsigned int*)ei, flags);

    k_wfrag<<<64, 256, 0, stream>>>(W1, flags, 128, 16384, whf1, wlf1);
    k_wfrag<<<64, 256, 0, stream>>>(W2, flags, 128, 16384, whf2, wlf2);
    k_wfrag<<<256, 256, 0, stream>>>(W3, flags, 512, 65536, whf3, wlf3);

    const int egrid = (EP + 255) / 256;
    const int nblk  = (N + 1023) / 1024;
    k_hist<<<egrid, 256, 0, stream>>>(ei, flags, deg, E, N);
    k_scan_a<<<nblk, 1024, 0, stream>>>(deg, coff, part, N);
    k_scan_b<<<1, 1024, 0, stream>>>(part, coff, nblk, N);
    k_scan_c<<<nblk, 1024, 0, stream>>>(coff, part, N);
    k_scatter<<<egrid, 256, 0, stream>>>(ei, flags, coff, cpos, csrc, E, N);

    const int ggrid = (N + 63) / 64;
    const int ngrid = (N + 3) / 4;

    // ---- layer 1
    k_gemm<true, 0><<<dim3(ggrid, 1), 256, 0, stream>>>(x, whf1, wlf1, h16_12, 128,
                                                        ssrc, sdst, as1, ad1, flags, N);
    k_agg<0><<<ngrid, 256, 0, stream>>>(coff, csrc, ssrc, sdst, h16_12, b1, x, flags, x1b, N);

    // ---- layer 2
    k_gemm<false, 0><<<dim3(ggrid, 1), 256, 0, stream>>>(x1b, whf2, wlf2, h16_12, 128,
                                                         ssrc, sdst, as2, ad2, flags, N);
    k_agg<1><<<ngrid, 256, 0, stream>>>(coff, csrc, ssrc, sdst, h16_12, b2, x1b, flags, x2b, N);

    // ---- layer 3: all 4 heads in one GEMM (grid.y=4) + one fused agg
    k_gemm<false, 1><<<dim3(ggrid, 4), 256, 0, stream>>>(x2b, whf3, wlf3, h16all, 512,
                                                         ssrc, sdst, as3, ad3, flags, N);
    k_agg<3><<<ngrid, 256, 0, stream>>>(coff, csrc, ssrc, sdst, h16all, b3, x2b, flags, d_out, N);
}